// Round 9
// baseline (280.319 us; speedup 1.0000x reference)
//
#include <hip/hip_runtime.h>
#include <hip/hip_bf16.h>
#include <math.h>

#define N_K 5292
#define N_KP 5376     // N_K padded to multiple of 64 for permuted V layout
#define N_Q 1344
#define NH_KD 128
#define NROWS 21504   // 2*8*1344 (b,h,q) rows of partials
#define NSPLIT 8      // K-splits per (b,h) plane
#define LOG2E 1.4426950408889634f
#define MSTAT 16.0f   // static softmax shift (log2 domain), in QK MFMA C-operand

typedef float f32x4 __attribute__((ext_vector_type(4)));
typedef short short8 __attribute__((ext_vector_type(8)));

__device__ __forceinline__ float fexp2(float x) {
#if __has_builtin(__builtin_amdgcn_exp2f)
    return __builtin_amdgcn_exp2f(x);
#else
    return exp2f(x);
#endif
}

// packed f32x2 -> bf16x2 (v_cvt_pk_bf16_f32); a in low 16 bits
__device__ __forceinline__ unsigned pk_bf16(float a, float b) {
    union { __hip_bfloat162 h; unsigned u; } c;
    c.h = __float22bfloat162_rn(make_float2(a, b));
    return c.u;
}
__device__ __forceinline__ unsigned short f2bf(float a) {
    return (unsigned short)pk_bf16(a, 0.f);
}

// ---- one-shot fp32 -> bf16 conversion of X, kv_w, q_w  (+ stats zero tail block) ----
__global__ __launch_bounds__(256) void prep_bf16(
    const float* __restrict__ X, const float* __restrict__ kv_w,
    const float* __restrict__ q_w,
    unsigned short* __restrict__ Xb, float* __restrict__ sums)
{
    int i = blockIdx.x * 256 + threadIdx.x;   // float4 index into concatenated space
    if (i >= 710144) {                        // stats zero: 256 threads x 8 floats = 2048
        int j = i - 710144;
        float4 z = make_float4(0.f, 0.f, 0.f, 0.f);
        *(float4*)(sums + (size_t)j * 8)     = z;
        *(float4*)(sums + (size_t)j * 8 + 4) = z;
        return;
    }
    const float* src;
    long off;
    if (i < 677376)       { src = X;      off = i; }
    else if (i < 701952)  { src = kv_w;   off = i - 677376; }
    else                  { src = q_w;    off = i - 701952; }
    float4 v = *(const float4*)(src + off * 4);
    *(uint2*)(Xb + (size_t)i * 4) = make_uint2(pk_bf16(v.x, v.y), pk_bf16(v.z, v.w));
}

// ---- GEMM 64x64 tile body: B panel staged ONCE in LDS, A fragments read
// directly from global (each A element is used by exactly one lane -> LDS
// round-trip for A was pure overhead). Barrier-free k-loop.
__device__ __forceinline__ void gemm_body_direct(
    const unsigned short* __restrict__ A, const unsigned short* __restrict__ W,
    long arow,               // per-LANE A row index (global), or -1 if invalid
    int n0,                  // B panel start row (output column base)
    unsigned short (*Bs)[264], f32x4 acc[4])
{
    const int t = threadIdx.x;
    const int lane = t & 63, g = lane >> 4, ln = lane & 15;

    // stage B panel: 64 rows x 256 cols bf16 = 2048 uint4, 8 per thread
    #pragma unroll
    for (int p = 0; p < 8; ++p) {
        int i = p * 256 + t;                 // uint4 index
        int row = i >> 5, c8 = (i & 31) * 8;
        *(uint4*)&Bs[row][c8] = *(const uint4*)(W + (size_t)(n0 + row) * 256 + c8);
    }
    __syncthreads();

    const unsigned short* aptr =
        (arow >= 0) ? (A + (size_t)arow * 256 + g * 8) : (const unsigned short*)0;

    #pragma unroll
    for (int k0 = 0; k0 < 256; k0 += 32) {
        short8 ah = (short8)0;
        if (aptr) ah = *(const short8*)(aptr + k0);
        #pragma unroll
        for (int nt = 0; nt < 4; ++nt) {
            short8 bh = *(const short8*)&Bs[nt * 16 + ln][k0 + g * 8];
            acc[nt] = __builtin_amdgcn_mfma_f32_16x16x32_bf16(ah, bh, acc[nt], 0, 0, 0);
        }
    }
}

// ---- fused column stats (sum/sumsq of this block's 64 rows) ----
__device__ __forceinline__ void gemm_stats(f32x4 acc[4], float* __restrict__ sums,
                                           int n0, int Ncols, float* scratch)
{
    const int t = threadIdx.x;
    const int w = t >> 6, lane = t & 63, g = lane >> 4, ln = lane & 15;
    float s4[4], q4[4];
    #pragma unroll
    for (int nt = 0; nt < 4; ++nt) {
        float s = acc[nt][0] + acc[nt][1] + acc[nt][2] + acc[nt][3];
        float q = fmaf(acc[nt][0], acc[nt][0], fmaf(acc[nt][1], acc[nt][1],
                  fmaf(acc[nt][2], acc[nt][2], acc[nt][3] * acc[nt][3])));
        s += __shfl_xor(s, 16); s += __shfl_xor(s, 32);
        q += __shfl_xor(q, 16); q += __shfl_xor(q, 32);
        s4[nt] = s; q4[nt] = q;
    }
    __syncthreads();
    float* st_s = scratch;
    float* st_q = scratch + 256;
    if (g == 0) {
        #pragma unroll
        for (int nt = 0; nt < 4; ++nt) {
            st_s[(w * 4 + nt) * 16 + ln] = s4[nt];
            st_q[(w * 4 + nt) * 16 + ln] = q4[nt];
        }
    }
    __syncthreads();
    if (t < 64) {
        int nt = t >> 4, c = t & 15;
        float a = 0.f, b2 = 0.f;
        #pragma unroll
        for (int ww = 0; ww < 4; ++ww) {
            a  += st_s[(ww * 4 + nt) * 16 + c];
            b2 += st_q[(ww * 4 + nt) * 16 + c];
        }
        atomicAdd(&sums[n0 + nt * 16 + c], a);
        atomicAdd(&sums[Ncols + n0 + nt * 16 + c], b2);
    }
}

// ---- kv + q GEMMs + folded prep (race-free Vpt tail zero, bias remap) ----
__global__ __launch_bounds__(256) void gemm_qkv(
    const unsigned short* __restrict__ Xb, const unsigned short* __restrict__ kvWb,
    const unsigned short* __restrict__ qWb,
    const float* __restrict__ bias_table, const int* __restrict__ bias_idxs, int n_off,
    unsigned short* __restrict__ Kp, unsigned short* __restrict__ Vpt,
    float* __restrict__ bt_r,
    float* __restrict__ q_y, float* __restrict__ sums_kv, float* __restrict__ sums_q)
{
    __shared__ unsigned short Bs[64][264];   // 33792 B (pad to 264 -> 2-way-free banks)
    const int t = threadIdx.x;
    const int w = t >> 6, lane = t & 63, g = lane >> 4, ln = lane & 15;
    int id = blockIdx.x;

    if (id >= 1104) {
        id -= 1104;
        if (id < 168) {           // zero the 84 never-written Vpt slots per row
            int i = id * 256 + t; // 512 rows x 84 slots = 43008 (exact)
            int row = i / 84, j = i - row * 84;
            int slot;
            if (j < 20) {         // group [5248,5312): slots of keys 5292..5311
                int kap = 44 + j;
                slot = 5248 + (((kap & 15) << 2) | (kap >> 4));
            } else {              // group [5312,5376): fully padding
                slot = 5312 + (j - 20);
            }
            Vpt[(size_t)row * N_KP + slot] = 0;
        } else {                  // bias remap: bt_r[h][dr*84+dc] = bias * log2e
            int i = (id - 168) * 256 + t;
            if (i < 8 * N_K) {
                int h = i / N_K, j = i - h * N_K;
                bt_r[i] = bias_table[h * n_off + bias_idxs[j]] * LOG2E;
            }
        }
        return;
    }

    f32x4 acc[4];
    #pragma unroll
    for (int nt = 0; nt < 4; ++nt) acc[nt] = (f32x4){0.f, 0.f, 0.f, 0.f};

    if (id < 1008) {            // kv: mtiles=166, nblk=6
        const int xcd = id & 7, id8 = id >> 3;
        const int my = xcd + (id8 / 6) * 8, ny = id8 % 6;
        if (my >= 166) return;
        const int m0 = my * 64, n0 = ny * 64;
        int arow0 = m0 + w * 16 + ln;                 // this lane's A row
        long arow = (arow0 < 10584) ? arow0 : -1;
        gemm_body_direct(Xb, kvWb, arow, n0, Bs, acc);

        #pragma unroll
        for (int nt = 0; nt < 4; ++nt) {
            int c = n0 + nt * 16 + ln;
            int hh = c / 48, cc = c - 48 * hh;
            #pragma unroll
            for (int reg = 0; reg < 4; ++reg) {
                int mr = m0 + w * 16 + g * 4 + reg;
                if (mr < 10584) {
                    int bb = mr >= N_K;
                    int key = mr - bb * N_K;
                    unsigned short v16 = f2bf(acc[nt][reg]);
                    if (cc < 16) {
                        Kp[((size_t)(bb * 8 + hh) * N_K + key) * 16 + cc] = v16;
                    } else {
                        int kap = key & 63;
                        int keyp = (key & ~63) | (((kap & 15) << 2) | (kap >> 4));
                        Vpt[((size_t)(bb * 8 + hh) * 32 + cc - 16) * N_KP + keyp] = v16;
                    }
                }
            }
        }
        gemm_stats(acc, sums_kv, n0, 384, (float*)&Bs[0][0]);
    } else {                    // q: mtiles=42, nblk=2 (strided subsample rows)
        id -= 1008;
        const int xcd = id & 7, id8 = id >> 3;
        const int my = xcd + (id8 / 2) * 8, ny = id8 % 2;
        if (my >= 42) return;
        const int m0 = my * 64, n0 = ny * 64;
        int mrow = m0 + w * 16 + ln;                  // this lane's output row
        int bb = mrow / N_Q;
        int i = mrow - bb * N_Q;
        long arow = (long)(bb * N_K + (i / 42) * 168 + (i % 42) * 2);
        gemm_body_direct(Xb, qWb, arow, n0, Bs, acc);

        #pragma unroll
        for (int nt = 0; nt < 4; ++nt)
            #pragma unroll
            for (int reg = 0; reg < 4; ++reg) {
                int mr = m0 + w * 16 + g * 4 + reg;
                q_y[(size_t)mr * 128 + n0 + nt * 16 + ln] = acc[nt][reg];
            }
        gemm_stats(acc, sums_q, n0, 128, (float*)&Bs[0][0]);
    }
}

// ---- proj GEMM (A bf16 attn_o direct, W bf16 staged once) ----
__global__ __launch_bounds__(256) void gemm_proj(
    const unsigned short* __restrict__ Ap, const unsigned short* __restrict__ Wp,
    float* __restrict__ Y, float* __restrict__ sums)
{
    __shared__ unsigned short Bs[64][264];
    const int t = threadIdx.x;
    const int w = t >> 6, lane = t & 63, g = lane >> 4, ln = lane & 15;
    const int id = blockIdx.x;
    const int xcd = id & 7, id8 = id >> 3;
    const int my = xcd + (id8 / 8) * 8, ny = id8 % 8;
    if (my >= 42) return;
    const int m0 = my * 64, n0 = ny * 64;

    f32x4 acc[4];
    #pragma unroll
    for (int nt = 0; nt < 4; ++nt) acc[nt] = (f32x4){0.f, 0.f, 0.f, 0.f};
    gemm_body_direct(Ap, Wp, (long)(m0 + w * 16 + ln), n0, Bs, acc);

    #pragma unroll
    for (int nt = 0; nt < 4; ++nt)
        #pragma unroll
        for (int reg = 0; reg < 4; ++reg) {
            int mr = m0 + w * 16 + g * 4 + reg;
            Y[(size_t)mr * 512 + n0 + nt * 16 + ln] = acc[nt][reg];
        }
    gemm_stats(acc, sums, n0, 512, (float*)&Bs[0][0]);
}

// ---- MFMA flash attention: 8-way K split, BARRIER-FREE key loop.
// K/V fragments read directly from global (L2-resident, XCD-pinned via h=id&7).
// LDS holds only the mirrored bias table + per-wave P_s (13864 B -> 8 blocks/CU).
// grid 2688: h=id&7, z=(id>>3)&15 (b*8+ks), qt=id>>7.
__global__ __launch_bounds__(256, 8) void attn_mfma(
    const unsigned short* __restrict__ Kp, const unsigned short* __restrict__ Vpt,
    const float* __restrict__ q_y, const float* __restrict__ sums_q,
    const float* __restrict__ q_g, const float* __restrict__ q_b,
    const float* __restrict__ sums_kv, const float* __restrict__ kv_g,
    const float* __restrict__ bt_r,
    float* __restrict__ pl, float* __restrict__ pacc)
{
    const int id = blockIdx.x;
    const int h = id & 7;
    const int z = (id >> 3) & 15;
    const int qt = id >> 7;
    const int b = z >> 3, ks = z & 7;
    const int t = threadIdx.x;
    const int w = t >> 6, lane = t & 63, g = lane >> 4, ln = lane & 15;

    __shared__ unsigned short btm_s[14 * 166]; // 4648 B mirrored bias (bf16)
    __shared__ unsigned short P_s[4][16][72];  // 9216 B (per wave; no cross-wave use)

    const int q0 = qt * 64;
    // tile-quantized split: 83 total tiles, split ks gets tiles [t0, t1)
    const int t0 = (ks * 83) >> 3;
    const int t1 = ((ks + 1) * 83) >> 3;
    const int kstart = t0 * 64;
    const int kend0 = t1 * 64;
    const int kend = kend0 < N_K ? kend0 : N_K;
    const int ntiles = t1 - t0;
    const bool tail = (ks == 7);

    // mirrored-window extents: d_r = rq2 - kr ranges [dmin_r, ...]; rows <= 14
    const int kr0 = kstart / 84;
    const int kr1 = (kend - 1) / 84;
    const int rq2min = (q0 / 42) * 2;
    const int rq2max = ((q0 + 63) / 42) * 2;
    const int dmin_r = rq2min - kr1;
    const int rows = (rq2max - kr0) - dmin_r + 1;    // <= 14
    const int nb = rows * 166;
    const unsigned mxb = (unsigned)((nb - 1) * 2);   // byte clamp (tail-last tile only)
    {   // stage mirrored bf16 bias: btm[j*166+i] = bf16(bt[|dmin_r+j|*84 + |i-83|])
        const float* src = bt_r + h * N_K;
        for (int j = t; j < nb; j += 256) {
            int rr = j / 166, ii = j - rr * 166;
            int dr = dmin_r + rr; dr = dr < 0 ? -dr : dr;
            int dc = ii - 83; dc = dc < 0 ? -dc : dc;
            btm_s[j] = f2bf(src[dr * 84 + dc]);
        }
    }

    // Q A-fragment: q-BN (0.25*log2e folded) times K-channel BN scale
    short8 qfrag = (short8)0;
    if (lane < 32) {
        const float invq = 1.f / 2688.f, invk = 1.f / 10584.f;
        const float post = 0.25f * LOG2E;
        const int c0 = h * 16 + g * 8;
        const int ck = h * 48 + g * 8;
        const float* qp = q_y + (size_t)(b * N_Q + q0 + w * 16 + ln) * NH_KD + c0;
        float vv[8];
        #pragma unroll
        for (int j = 0; j < 8; ++j) {
            float mu  = sums_q[c0 + j] * invq;
            float var = fmaf(-mu, mu, sums_q[128 + c0 + j] * invq);
            float s   = q_g[c0 + j] * rsqrtf(var + 1e-5f) * post;
            float vq  = fmaf(qp[j], s, fmaf(-mu, s, q_b[c0 + j] * post));
            float muk = sums_kv[ck + j] * invk;
            float vrk = fmaf(-muk, muk, sums_kv[384 + ck + j] * invk);
            float sk  = kv_g[ck + j] * rsqrtf(vrk + 1e-5f);
            vv[j] = vq * sk;
        }
        union { short8 s; unsigned u[4]; } qf;
        qf.u[0] = pk_bf16(vv[0], vv[1]); qf.u[1] = pk_bf16(vv[2], vv[3]);
        qf.u[2] = pk_bf16(vv[4], vv[5]); qf.u[3] = pk_bf16(vv[6], vv[7]);
        qfrag = qf.s;
    }
    __syncthreads();   // bias table ready (only barrier in the kernel)

    // all-ones bf16 B-fragment (for MFMA row-sum of P -> l)
    union { short8 s; unsigned u[4]; } onef;
    #pragma unroll
    for (int j = 0; j < 4; ++j) onef.u[j] = 0x3F803F80u;
    const short8 ones = onef.s;

    // per-reg base BYTE offset into mirrored bf16 table (constant over key loop)
    int baseb[4];
    #pragma unroll
    for (int reg = 0; reg < 4; ++reg) {
        int qg = q0 + w * 16 + g * 4 + reg;
        int rq2 = (qg / 42) * 2;
        int cq2 = (qg % 42) * 2;
        baseb[reg] = ((rq2 - dmin_r) * 166 + cq2 + 83) * 2;
    }
    // per-subtile BYTE offset, advanced incrementally: off = -(kr*166 + kc)*2
    int offb[4], kcc[4];
    #pragma unroll
    for (int st = 0; st < 4; ++st) {
        int kg = kstart + st * 16 + ln;
        int okr = kg / 84;
        kcc[st] = kg - okr * 84;
        offb[st] = -(okr * 166 + kcc[st]) * 2;
    }

    // direct-global fragment pointers (L2-resident, XCD-pinned)
    const unsigned short* kp_u16 = Kp + (size_t)(b * 8 + h) * N_K * 16;
    const unsigned short* vb0 = Vpt + (size_t)(b * 8 + h) * 32 * N_KP
                                    + (size_t)ln * N_KP + kstart + g * 8;
    const unsigned short* vb1 = vb0 + (size_t)16 * N_KP;

    f32x4 acc0 = {0.f, 0.f, 0.f, 0.f}, acc1 = {0.f, 0.f, 0.f, 0.f};
    f32x4 accL = {0.f, 0.f, 0.f, 0.f};              // l via MFMA(P, ones)
    const f32x4 minit = {-MSTAT, -MSTAT, -MSTAT, -MSTAT};  // static shift via C operand

    for (int it = 0; it < ntiles; ++it) {
        const int k0 = kstart + it * 64;

        // QK^T: K fragments straight from global (coalesced 512B per st per wave)
        f32x4 sf[4];
        #pragma unroll
        for (int st = 0; st < 4; ++st) {
            short8 bf = (short8)0;
            if (lane < 32) {
                int key = k0 + st * 16 + ln;
                key = key > N_K - 1 ? N_K - 1 : key;
                bf = *(const short8*)(kp_u16 + (size_t)key * 16 + g * 8);
            }
            sf[st] = __builtin_amdgcn_mfma_f32_16x16x32_bf16(qfrag, bf, minit, 0, 0, 0);
        }

        // p = exp2(qk - MSTAT + bias). Clamp+mask only in the last tile of tail
        // (ks==7) blocks; all other indices provably in-window.
        float pv[4][4];
        const bool clampit = tail && (it == ntiles - 1);
        if (!clampit) {
            #pragma unroll
            for (int st = 0; st < 4; ++st) {
                #pragma unroll
                for (int reg = 0; reg < 4; ++reg) {
                    unsigned ub = (unsigned)(baseb[reg] + offb[st]);
                    unsigned short bu = *(const unsigned short*)((const char*)btm_s + ub);
                    float bias = __uint_as_float(((unsigned)bu) << 16);
                    pv[st][reg] = fexp2(sf[st][reg] + bias);
                }
            }
        } else {
            #pragma unroll
            for (int st = 0; st < 4; ++st) {
                bool bad = (k0 + st * 16 + ln) >= N_K;
                #pragma unroll
                for (int reg = 0; reg < 4; ++reg) {
                    unsigned ub = (unsigned)(baseb[reg] + offb[st]);
                    ub = ub > mxb ? mxb : ub;
                    unsigned short bu = *(const unsigned short*)((const char*)btm_s + ub);
                    float bias = __uint_as_float(((unsigned)bu) << 16);
                    pv[st][reg] = bad ? 0.f : fexp2(sf[st][reg] + bias);
                }
            }
        }

        // P -> LDS (per-wave buffer; slot-permuted to match V layout)
        #pragma unroll
        for (int reg = 0; reg < 4; ++reg) {
            uint2 pw = make_uint2(pk_bf16(pv[0][reg], pv[1][reg]),
                                  pk_bf16(pv[2][reg], pv[3][reg]));
            *(uint2*)&P_s[w][g * 4 + reg][4 * ln] = pw;
        }
        __asm__ __volatile__("" ::: "memory");   // order P_s RAW (uint2 write, short8 read)

        // PV + l row-sum; V fragments straight from global (L2)
        #pragma unroll
        for (int kt = 0; kt < 2; ++kt) {
            short8 af = *(const short8*)&P_s[w][ln][g * 8 + kt * 32];
            short8 b0 = *(const short8*)(vb0 + it * 64 + kt * 32);
            short8 b1 = *(const short8*)(vb1 + it * 64 + kt * 32);
            acc0 = __builtin_amdgcn_mfma_f32_16x16x32_bf16(af, b0, acc0, 0, 0, 0);
            acc1 = __builtin_amdgcn_mfma_f32_16x16x32_bf16(af, b1, acc1, 0, 0, 0);
            accL = __builtin_amdgcn_mfma_f32_16x16x32_bf16(af, ones, accL, 0, 0, 0);
        }

        // advance key geometry: key += 64 => offb -= 128 B (or 292 B on row wrap)
        #pragma unroll
        for (int st = 0; st < 4; ++st) {
            kcc[st] += 64;
            if (kcc[st] >= 84) { kcc[st] -= 84; offb[st] -= 292; }
            else offb[st] -= 128;
        }
    }

    // accL[reg]: every col holds the same row-sum (C row = A row = q-row g*4+reg)
    const int rbase = (b * 8 + h) * N_Q + q0 + w * 16;
    #pragma unroll
    for (int reg = 0; reg < 4; ++reg) {
        int prow = ks * NROWS + rbase + g * 4 + reg;
        pacc[(size_t)prow * 32 + ln]      = acc0[reg];
        pacc[(size_t)prow * 32 + 16 + ln] = acc1[reg];
        if (ln == 0) pl[prow] = accL[reg];
    }
}

// ---- combine 8 partials + V-BN (folded) + hardswish -> bf16 plane, x4 vectorized.
// Extra 128 blocks (>= 672) convert proj_w -> bf16 into the now-dead q_y region.
__global__ __launch_bounds__(256) void combine_kernel(const float* __restrict__ pl,
                                                      const float* __restrict__ pacc,
                                                      const float* __restrict__ sums_kv,
                                                      const float* __restrict__ kv_g,
                                                      const float* __restrict__ kv_b,
                                                      unsigned short* __restrict__ attn_o,
                                                      const float* __restrict__ proj_w,
                                                      unsigned short* __restrict__ projWb)
{
    if (blockIdx.x >= 672) {   // proj_w fp32 -> bf16 (512*256 = 32768 float4, 128 blocks)
        int i = (blockIdx.x - 672) * 256 + threadIdx.x;
        float4 v = *(const float4*)(proj_w + (size_t)i * 4);
        *(uint2*)(projWb + (size_t)i * 4) = make_uint2(pk_bf16(v.x, v.y), pk_bf16(v.z, v.w));
        return;
    }
    int idx = blockIdx.x * 256 + threadIdx.x;    // NROWS*8 items, 4 channels each
    int r = idx >> 3, e4 = (idx & 7) * 4;
    float L = 0.f;
    float vs[4] = {0.f, 0.f, 0.f, 0.f};
    size_t o = (size_t)r * 32 + e4;
    #pragma unroll
    for (int s2 = 0; s2 < NSPLIT; ++s2) {
        L += pl[(size_t)s2 * NROWS + r];
        float4 vv = *(const float4*)(pacc + (size_t)s2 * NROWS * 32 + o);
        vs[0] += vv.x; vs[1] += vv.y; vs[2] += vv.z; vs[3] += vv.w;
    }
    float invL = 1.f / L;
    int q = r % N_Q;
    int bh = r / N_Q;
    int hh = bh & 7, b = bh >> 3;
    const int ch = hh * 48 + 16 + e4;
    const float invk = 1.f / 10584.f;
    float hs[4];
    #pragma unroll
    for (int u = 0; u < 4; ++u) {
        float v = vs[u];
        float mu  = sums_kv[ch + u] * invk;
        float var = fmaf(-mu, mu, sums_kv[384 + ch + u] * invk);
        float s   = kv_g[ch + u] * rsqrtf(var + 1e-5f);
        float tt  = fmaf(-mu, s, kv_b[ch + u]);
        v = fmaf(s, v * invL, tt);
        hs[u] = v * fminf(fmaxf(v + 3.f, 0.f), 6.f) * (1.f / 6.f);
    }
    *(uint2*)(attn_o + (size_t)(b * N_Q + q) * 256 + hh * 32 + e4) =
        make_uint2(pk_bf16(hs[0], hs[1]), pk_bf16(hs[2], hs[3]));
}

// ---- final BN apply ----
__global__ __launch_bounds__(256) void norm_apply(
    const float* __restrict__ Y, const float* __restrict__ sums,
    const float* __restrict__ g, const float* __restrict__ bb,
    float* __restrict__ out, int rows, int cols, float inv_rows)
{
    __shared__ float sc_s[64], sh_s[64];
    const int t = threadIdx.x;
    const int c0 = blockIdx.x * 64;
    if (t < 64) {
        int c = c0 + t;
        float mu  = sums[c] * inv_rows;
        float var = fmaf(-mu, mu, sums[cols + c] * inv_rows);
        float s   = g[c] * rsqrtf(var + 1e-5f);
        sc_s[t] = s;
        sh_s[t] = fmaf(-mu, s, bb[c]);
    }
    __syncthreads();
    const int c4 = (t & 15) * 4;
    float4 scv = *(const float4*)&sc_s[c4];
    float4 shv = *(const float4*)&sh_s[c4];
    for (int r = blockIdx.y * 16 + (t >> 4); r < rows; r += gridDim.y * 16) {
        size_t off = (size_t)r * cols + c0 + c4;
        float4 v = *(const float4*)(Y + off);
        v.x = fmaf(v.x, scv.x, shv.x);
        v.y = fmaf(v.y, scv.y, shv.y);
        v.z = fmaf(v.z, scv.z, shv.z);
        v.w = fmaf(v.w, scv.w, shv.w);
        *(float4*)(out + off) = v;
    }
}

extern "C" void kernel_launch(void* const* d_in, const int* in_sizes, int n_in,
                              void* d_out, int out_size, void* d_ws, size_t ws_size,
                              hipStream_t stream) {
    (void)n_in; (void)out_size; (void)ws_size;
    const float* x      = (const float*)d_in[0];
    const float* kv_w   = (const float*)d_in[1];
    const float* kv_g   = (const float*)d_in[2];
    const float* kv_b   = (const float*)d_in[3];
    const float* q_w    = (const float*)d_in[4];
    const float* q_g    = (const float*)d_in[5];
    const float* q_b    = (const float*)d_in[6];
    const float* proj_w = (const float*)d_in[7];
    const float* proj_g = (const float*)d_in[8];
    const float* proj_b = (const float*)d_in[9];
    const float* bias_table = (const float*)d_in[10];
    const int*   bias_idxs  = (const int*)d_in[11];
    const int    n_off = in_sizes[10] / 8;
    float* out = (float*)d_out;

    float* ws = (float*)d_ws;
    float* q_y  = ws;                                       // 344,064 f
    float* pacc = q_y + 2688 * 128;                         // 8*NROWS*32 = 5,505,024 f
    float* proj_y = pacc;
    float* pl = pacc + (size_t)NSPLIT * NROWS * 32;         // 8*NROWS = 172,032 f
    unsigned short* attn_o = (unsigned short*)(pl + (size_t)NSPLIT * NROWS);  // 688,128 u16
    unsigned short* Kp  = attn_o + 2688 * 256;              // 2*8*5292*16 u16
    unsigned short* Vpt = Kp + 2 * 8 * N_K * 16;            // 2*8*32*N_KP u16
    float* sums_kv = (float*)(Vpt + 2 * 8 * 32 * N_KP);     // 768
    float* sums_q  = sums_kv + 768;                         // 256
    float* sums_p  = sums_q + 256;                          // 1024  (2048 f contiguous)
    float* bt_r    = sums_p + 1024;                         // 8*5292

    // bf16 staging planes:
    //  Xb/kvWb/qWb overlay pacc  (consumed by gemm_qkv BEFORE attn_mfma clobbers pacc)
    //  projWb overlays q_y       (written by combine_kernel AFTER attn_mfma's last q_y read)
    unsigned short* Xb     = (unsigned short*)pacc;         // 10584*256 u16
    unsigned short* kvWb   = Xb + 10584 * 256;              // 384*256
    unsigned short* qWb    = kvWb + 384 * 256;              // 128*256
    unsigned short* projWb = (unsigned short*)q_y;          // 512*256 u16

    // 1) one-shot fp32 -> bf16 conversion of X + kv/q weights; tail block zeroes stats
    prep_bf16<<<2775, 256, 0, stream>>>(x, kv_w, q_w, Xb, sums_kv);
    // 2) kv + q GEMMs (B-once-in-LDS, A-direct, barrier-free) + prep tails
    gemm_qkv<<<1104 + 168 + 166, 256, 0, stream>>>(Xb, kvWb, qWb, bias_table, bias_idxs,
                                                   n_off, Kp, Vpt, bt_r,
                                                   q_y, sums_kv, sums_q);
    // 3) flash attention: 8-way K split, barrier-free, direct-global K/V (L2)
    attn_mfma<<<2688, 256, 0, stream>>>(Kp, Vpt, q_y, sums_q, q_g, q_b,
                                        sums_kv, kv_g, bt_r, pl, pacc);
    // 4) combine 8 partials + V-BN + hardswish -> bf16; tail converts proj_w -> bf16
    combine_kernel<<<672 + 128, 256, 0, stream>>>(pl, pacc, sums_kv, kv_g, kv_b, attn_o,
                                                  proj_w, projWb);
    // 5) proj GEMM (B-once-in-LDS, A-direct)
    gemm_proj<<<384, 256, 0, stream>>>(attn_o, projWb, proj_y, sums_p);
    // 6) final BN -> out
    norm_apply<<<dim3(8, 84), 256, 0, stream>>>(proj_y, sums_p, proj_g, proj_b, out,
                                                2688, 512, 1.f / 2688.f);
}

// Round 10
// 210.826 us; speedup vs baseline: 1.3296x; 1.3296x over previous
//
#include <hip/hip_runtime.h>
#include <hip/hip_bf16.h>
#include <math.h>

#define N_K 5292
#define N_KP 5376     // N_K padded to multiple of 64 for permuted V layout
#define N_Q 1344
#define NH_KD 128
#define NROWS 21504   // 2*8*1344 (b,h,q) rows of partials
#define NSPLIT 8      // K-splits per (b,h) plane
#define LOG2E 1.4426950408889634f
#define MSTAT 16.0f   // static softmax shift (log2 domain), in QK MFMA C-operand

typedef float f32x4 __attribute__((ext_vector_type(4)));
typedef short short8 __attribute__((ext_vector_type(8)));

__device__ __forceinline__ float fexp2(float x) {
#if __has_builtin(__builtin_amdgcn_exp2f)
    return __builtin_amdgcn_exp2f(x);
#else
    return exp2f(x);
#endif
}

// packed f32x2 -> bf16x2 (v_cvt_pk_bf16_f32); a in low 16 bits
__device__ __forceinline__ unsigned pk_bf16(float a, float b) {
    union { __hip_bfloat162 h; unsigned u; } c;
    c.h = __float22bfloat162_rn(make_float2(a, b));
    return c.u;
}
__device__ __forceinline__ unsigned short f2bf(float a) {
    return (unsigned short)pk_bf16(a, 0.f);
}

// ---- one-shot fp32 -> bf16 conversion of X, kv_w, q_w  (+ stats zero tail block) ----
__global__ __launch_bounds__(256) void prep_bf16(
    const float* __restrict__ X, const float* __restrict__ kv_w,
    const float* __restrict__ q_w,
    unsigned short* __restrict__ Xb, float* __restrict__ sums)
{
    int i = blockIdx.x * 256 + threadIdx.x;   // float4 index into concatenated space
    if (i >= 710144) {                        // stats zero: 256 threads x 8 floats = 2048
        int j = i - 710144;
        float4 z = make_float4(0.f, 0.f, 0.f, 0.f);
        *(float4*)(sums + (size_t)j * 8)     = z;
        *(float4*)(sums + (size_t)j * 8 + 4) = z;
        return;
    }
    const float* src;
    long off;
    if (i < 677376)       { src = X;      off = i; }
    else if (i < 701952)  { src = kv_w;   off = i - 677376; }
    else                  { src = q_w;    off = i - 701952; }
    float4 v = *(const float4*)(src + off * 4);
    *(uint2*)(Xb + (size_t)i * 4) = make_uint2(pk_bf16(v.x, v.y), pk_bf16(v.z, v.w));
}

// ---- GEMM 64x64 tile body: B panel staged ONCE in LDS, A fragments read
// directly from global (each A element is used by exactly one lane -> LDS
// round-trip for A was pure overhead). Barrier-free k-loop. (R9-measured keep.)
__device__ __forceinline__ void gemm_body_direct(
    const unsigned short* __restrict__ A, const unsigned short* __restrict__ W,
    long arow,               // per-LANE A row index (global), or -1 if invalid
    int n0,                  // B panel start row (output column base)
    unsigned short (*Bs)[264], f32x4 acc[4])
{
    const int t = threadIdx.x;
    const int lane = t & 63, g = lane >> 4, ln = lane & 15;

    // stage B panel: 64 rows x 256 cols bf16 = 2048 uint4, 8 per thread
    #pragma unroll
    for (int p = 0; p < 8; ++p) {
        int i = p * 256 + t;                 // uint4 index
        int row = i >> 5, c8 = (i & 31) * 8;
        *(uint4*)&Bs[row][c8] = *(const uint4*)(W + (size_t)(n0 + row) * 256 + c8);
    }
    __syncthreads();

    const unsigned short* aptr =
        (arow >= 0) ? (A + (size_t)arow * 256 + g * 8) : (const unsigned short*)0;

    #pragma unroll
    for (int k0 = 0; k0 < 256; k0 += 32) {
        short8 ah = (short8)0;
        if (aptr) ah = *(const short8*)(aptr + k0);
        #pragma unroll
        for (int nt = 0; nt < 4; ++nt) {
            short8 bh = *(const short8*)&Bs[nt * 16 + ln][k0 + g * 8];
            acc[nt] = __builtin_amdgcn_mfma_f32_16x16x32_bf16(ah, bh, acc[nt], 0, 0, 0);
        }
    }
}

// ---- fused column stats (sum/sumsq of this block's 64 rows) ----
__device__ __forceinline__ void gemm_stats(f32x4 acc[4], float* __restrict__ sums,
                                           int n0, int Ncols, float* scratch)
{
    const int t = threadIdx.x;
    const int w = t >> 6, lane = t & 63, g = lane >> 4, ln = lane & 15;
    float s4[4], q4[4];
    #pragma unroll
    for (int nt = 0; nt < 4; ++nt) {
        float s = acc[nt][0] + acc[nt][1] + acc[nt][2] + acc[nt][3];
        float q = fmaf(acc[nt][0], acc[nt][0], fmaf(acc[nt][1], acc[nt][1],
                  fmaf(acc[nt][2], acc[nt][2], acc[nt][3] * acc[nt][3])));
        s += __shfl_xor(s, 16); s += __shfl_xor(s, 32);
        q += __shfl_xor(q, 16); q += __shfl_xor(q, 32);
        s4[nt] = s; q4[nt] = q;
    }
    __syncthreads();
    float* st_s = scratch;
    float* st_q = scratch + 256;
    if (g == 0) {
        #pragma unroll
        for (int nt = 0; nt < 4; ++nt) {
            st_s[(w * 4 + nt) * 16 + ln] = s4[nt];
            st_q[(w * 4 + nt) * 16 + ln] = q4[nt];
        }
    }
    __syncthreads();
    if (t < 64) {
        int nt = t >> 4, c = t & 15;
        float a = 0.f, b2 = 0.f;
        #pragma unroll
        for (int ww = 0; ww < 4; ++ww) {
            a  += st_s[(ww * 4 + nt) * 16 + c];
            b2 += st_q[(ww * 4 + nt) * 16 + c];
        }
        atomicAdd(&sums[n0 + nt * 16 + c], a);
        atomicAdd(&sums[Ncols + n0 + nt * 16 + c], b2);
    }
}

// ---- kv + q GEMMs + folded prep (race-free Vpt tail zero, bias remap) ----
__global__ __launch_bounds__(256) void gemm_qkv(
    const unsigned short* __restrict__ Xb, const unsigned short* __restrict__ kvWb,
    const unsigned short* __restrict__ qWb,
    const float* __restrict__ bias_table, const int* __restrict__ bias_idxs, int n_off,
    unsigned short* __restrict__ Kp, unsigned short* __restrict__ Vpt,
    float* __restrict__ bt_r,
    float* __restrict__ q_y, float* __restrict__ sums_kv, float* __restrict__ sums_q)
{
    __shared__ unsigned short Bs[64][264];   // 33792 B
    const int t = threadIdx.x;
    const int w = t >> 6, lane = t & 63, g = lane >> 4, ln = lane & 15;
    int id = blockIdx.x;

    if (id >= 1104) {
        id -= 1104;
        if (id < 168) {           // zero the 84 never-written Vpt slots per row
            int i = id * 256 + t; // 512 rows x 84 slots = 43008 (exact)
            int row = i / 84, j = i - row * 84;
            int slot;
            if (j < 20) {         // group [5248,5312): slots of keys 5292..5311
                int kap = 44 + j;
                slot = 5248 + (((kap & 15) << 2) | (kap >> 4));
            } else {              // group [5312,5376): fully padding
                slot = 5312 + (j - 20);
            }
            Vpt[(size_t)row * N_KP + slot] = 0;
        } else {                  // bias remap: bt_r[h][dr*84+dc] = bias * log2e
            int i = (id - 168) * 256 + t;
            if (i < 8 * N_K) {
                int h = i / N_K, j = i - h * N_K;
                bt_r[i] = bias_table[h * n_off + bias_idxs[j]] * LOG2E;
            }
        }
        return;
    }

    f32x4 acc[4];
    #pragma unroll
    for (int nt = 0; nt < 4; ++nt) acc[nt] = (f32x4){0.f, 0.f, 0.f, 0.f};

    if (id < 1008) {            // kv: mtiles=166, nblk=6
        const int xcd = id & 7, id8 = id >> 3;
        const int my = xcd + (id8 / 6) * 8, ny = id8 % 6;
        if (my >= 166) return;
        const int m0 = my * 64, n0 = ny * 64;
        int arow0 = m0 + w * 16 + ln;                 // this lane's A row
        long arow = (arow0 < 10584) ? arow0 : -1;
        gemm_body_direct(Xb, kvWb, arow, n0, Bs, acc);

        #pragma unroll
        for (int nt = 0; nt < 4; ++nt) {
            int c = n0 + nt * 16 + ln;
            int hh = c / 48, cc = c - 48 * hh;
            #pragma unroll
            for (int reg = 0; reg < 4; ++reg) {
                int mr = m0 + w * 16 + g * 4 + reg;
                if (mr < 10584) {
                    int bb = mr >= N_K;
                    int key = mr - bb * N_K;
                    unsigned short v16 = f2bf(acc[nt][reg]);
                    if (cc < 16) {
                        Kp[((size_t)(bb * 8 + hh) * N_K + key) * 16 + cc] = v16;
                    } else {
                        int kap = key & 63;
                        int keyp = (key & ~63) | (((kap & 15) << 2) | (kap >> 4));
                        Vpt[((size_t)(bb * 8 + hh) * 32 + cc - 16) * N_KP + keyp] = v16;
                    }
                }
            }
        }
        gemm_stats(acc, sums_kv, n0, 384, (float*)&Bs[0][0]);
    } else {                    // q: mtiles=42, nblk=2 (strided subsample rows)
        id -= 1008;
        const int xcd = id & 7, id8 = id >> 3;
        const int my = xcd + (id8 / 2) * 8, ny = id8 % 2;
        if (my >= 42) return;
        const int m0 = my * 64, n0 = ny * 64;
        int mrow = m0 + w * 16 + ln;                  // this lane's output row
        int bb = mrow / N_Q;
        int i = mrow - bb * N_Q;
        long arow = (long)(bb * N_K + (i / 42) * 168 + (i % 42) * 2);
        gemm_body_direct(Xb, qWb, arow, n0, Bs, acc);

        #pragma unroll
        for (int nt = 0; nt < 4; ++nt)
            #pragma unroll
            for (int reg = 0; reg < 4; ++reg) {
                int mr = m0 + w * 16 + g * 4 + reg;
                q_y[(size_t)mr * 128 + n0 + nt * 16 + ln] = acc[nt][reg];
            }
        gemm_stats(acc, sums_q, n0, 128, (float*)&Bs[0][0]);
    }
}

// ---- proj GEMM (A bf16 attn_o direct, W bf16 staged once) ----
__global__ __launch_bounds__(256) void gemm_proj(
    const unsigned short* __restrict__ Ap, const unsigned short* __restrict__ Wp,
    float* __restrict__ Y, float* __restrict__ sums)
{
    __shared__ unsigned short Bs[64][264];
    const int t = threadIdx.x;
    const int w = t >> 6, lane = t & 63, g = lane >> 4, ln = lane & 15;
    const int id = blockIdx.x;
    const int xcd = id & 7, id8 = id >> 3;
    const int my = xcd + (id8 / 8) * 8, ny = id8 % 8;
    if (my >= 42) return;
    const int m0 = my * 64, n0 = ny * 64;

    f32x4 acc[4];
    #pragma unroll
    for (int nt = 0; nt < 4; ++nt) acc[nt] = (f32x4){0.f, 0.f, 0.f, 0.f};
    gemm_body_direct(Ap, Wp, (long)(m0 + w * 16 + ln), n0, Bs, acc);

    #pragma unroll
    for (int nt = 0; nt < 4; ++nt)
        #pragma unroll
        for (int reg = 0; reg < 4; ++reg) {
            int mr = m0 + w * 16 + g * 4 + reg;
            Y[(size_t)mr * 512 + n0 + nt * 16 + ln] = acc[nt][reg];
        }
    gemm_stats(acc, sums, n0, 512, (float*)&Bs[0][0]);
}

// ---- MFMA flash attention: 8-way K split; V staged in LDS (dbuf, coalesced),
// K read DIRECT from global (coalesced, L2-resident, XCD-pinned via h=id&7).
// LDS 23080 B; launch_bounds(256,6) leaves VGPR cap 85 (no spill).
// grid 2688: h=id&7, z=(id>>3)&15 (b*8+ks), qt=id>>7.
__global__ __launch_bounds__(256, 6) void attn_mfma(
    const unsigned short* __restrict__ Kp, const unsigned short* __restrict__ Vpt,
    const float* __restrict__ q_y, const float* __restrict__ sums_q,
    const float* __restrict__ q_g, const float* __restrict__ q_b,
    const float* __restrict__ sums_kv, const float* __restrict__ kv_g,
    const float* __restrict__ bt_r,
    float* __restrict__ pl, float* __restrict__ pacc)
{
    const int id = blockIdx.x;
    const int h = id & 7;
    const int z = (id >> 3) & 15;
    const int qt = id >> 7;
    const int b = z >> 3, ks = z & 7;
    const int t = threadIdx.x;
    const int w = t >> 6, lane = t & 63, g = lane >> 4, ln = lane & 15;

    __shared__ unsigned short btm_s[14 * 166]; // 4648 B mirrored bias (bf16)
    __shared__ unsigned short Vt_s[2][32][72]; // 9216 B (dbuf, b128-read free)
    __shared__ unsigned short P_s[4][16][72];  // 9216 B (per wave)

    const int q0 = qt * 64;
    // tile-quantized split: 83 total tiles, split ks gets tiles [t0, t1)
    const int t0 = (ks * 83) >> 3;
    const int t1 = ((ks + 1) * 83) >> 3;
    const int kstart = t0 * 64;
    const int kend0 = t1 * 64;
    const int kend = kend0 < N_K ? kend0 : N_K;
    const int ntiles = t1 - t0;
    const bool tail = (ks == 7);

    // mirrored-window extents: d_r = rq2 - kr ranges [dmin_r, ...]; rows <= 14
    const int kr0 = kstart / 84;
    const int kr1 = (kend - 1) / 84;
    const int rq2min = (q0 / 42) * 2;
    const int rq2max = ((q0 + 63) / 42) * 2;
    const int dmin_r = rq2min - kr1;
    const int rows = (rq2max - kr0) - dmin_r + 1;    // <= 14
    const int nb = rows * 166;
    const unsigned mxb = (unsigned)((nb - 1) * 2);   // byte clamp (tail-last tile only)
    {   // stage mirrored bf16 bias: btm[j*166+i] = bf16(bt[|dmin_r+j|*84 + |i-83|])
        const float* src = bt_r + h * N_K;
        for (int j = t; j < nb; j += 256) {
            int rr = j / 166, ii = j - rr * 166;
            int dr = dmin_r + rr; dr = dr < 0 ? -dr : dr;
            int dc = ii - 83; dc = dc < 0 ? -dc : dc;
            btm_s[j] = f2bf(src[dr * 84 + dc]);
        }
    }

    // Q A-fragment: q-BN (0.25*log2e folded) times K-channel BN scale
    short8 qfrag = (short8)0;
    if (lane < 32) {
        const float invq = 1.f / 2688.f, invk = 1.f / 10584.f;
        const float post = 0.25f * LOG2E;
        const int c0 = h * 16 + g * 8;
        const int ck = h * 48 + g * 8;
        const float* qp = q_y + (size_t)(b * N_Q + q0 + w * 16 + ln) * NH_KD + c0;
        float vv[8];
        #pragma unroll
        for (int j = 0; j < 8; ++j) {
            float mu  = sums_q[c0 + j] * invq;
            float var = fmaf(-mu, mu, sums_q[128 + c0 + j] * invq);
            float s   = q_g[c0 + j] * rsqrtf(var + 1e-5f) * post;
            float vq  = fmaf(qp[j], s, fmaf(-mu, s, q_b[c0 + j] * post));
            float muk = sums_kv[ck + j] * invk;
            float vrk = fmaf(-muk, muk, sums_kv[384 + ck + j] * invk);
            float sk  = kv_g[ck + j] * rsqrtf(vrk + 1e-5f);
            vv[j] = vq * sk;
        }
        union { short8 s; unsigned u[4]; } qf;
        qf.u[0] = pk_bf16(vv[0], vv[1]); qf.u[1] = pk_bf16(vv[2], vv[3]);
        qf.u[2] = pk_bf16(vv[4], vv[5]); qf.u[3] = pk_bf16(vv[6], vv[7]);
        qfrag = qf.s;
    }

    // all-ones bf16 B-fragment (for MFMA row-sum of P -> l)
    union { short8 s; unsigned u[4]; } onef;
    #pragma unroll
    for (int j = 0; j < 4; ++j) onef.u[j] = 0x3F803F80u;
    const short8 ones = onef.s;

    // per-reg base BYTE offset into mirrored bf16 table (constant over key loop)
    int baseb[4];
    #pragma unroll
    for (int reg = 0; reg < 4; ++reg) {
        int qg = q0 + w * 16 + g * 4 + reg;
        int rq2 = (qg / 42) * 2;
        int cq2 = (qg % 42) * 2;
        baseb[reg] = ((rq2 - dmin_r) * 166 + cq2 + 83) * 2;
    }
    // per-subtile BYTE offset, advanced incrementally: off = -(kr*166 + kc)*2
    int offb[4], kcc[4];
    #pragma unroll
    for (int st = 0; st < 4; ++st) {
        int kg = kstart + st * 16 + ln;
        int okr = kg / 84;
        kcc[st] = kg - okr * 84;
        offb[st] = -(okr * 166 + kcc[st]) * 2;
    }

    // K: direct-global fragment pointer (coalesced 32B/key, L2-resident)
    const unsigned short* kp_u16 = Kp + (size_t)(b * 8 + h) * N_K * 16;
    // V: LDS-staged (coalesced b128 stage; per-lane strided access stays in LDS)
    const int vrow = t >> 3, vc8 = (t & 7) * 8;
    const unsigned short* vptr = Vpt + (size_t)(b * 8 + h) * 32 * N_KP
                                     + (size_t)vrow * N_KP + kstart + vc8;

    uint4 vreg = *(const uint4*)vptr;
    *(uint4*)&Vt_s[0][vrow][vc8] = vreg;
    __syncthreads();   // V(0) + bias table ready

    f32x4 acc0 = {0.f, 0.f, 0.f, 0.f}, acc1 = {0.f, 0.f, 0.f, 0.f};
    f32x4 accL = {0.f, 0.f, 0.f, 0.f};              // l via MFMA(P, ones)
    const f32x4 minit = {-MSTAT, -MSTAT, -MSTAT, -MSTAT};  // static shift via C operand
    int p = 0;

    for (int it = 0; it < ntiles; ++it) {
        const int k0 = kstart + it * 64;
        const bool notlast = (it + 1 < ntiles);
        if (notlast) vreg = *(const uint4*)(vptr + 64);   // next V tile, issued early

        // QK^T: K fragments straight from global (st: 16 keys x 32B, coalesced)
        f32x4 sf[4];
        #pragma unroll
        for (int st = 0; st < 4; ++st) {
            short8 bf = (short8)0;
            if (lane < 32) {
                int key = k0 + st * 16 + ln;
                key = key > N_K - 1 ? N_K - 1 : key;
                bf = *(const short8*)(kp_u16 + (size_t)key * 16 + g * 8);
            }
            sf[st] = __builtin_amdgcn_mfma_f32_16x16x32_bf16(qfrag, bf, minit, 0, 0, 0);
        }

        // p = exp2(qk - MSTAT + bias). Clamp+mask only in the last tile of tail
        // (ks==7) blocks; all other indices provably in-window.
        float pv[4][4];
        const bool clampit = tail && (it == ntiles - 1);
        if (!clampit) {
            #pragma unroll
            for (int st = 0; st < 4; ++st) {
                #pragma unroll
                for (int reg = 0; reg < 4; ++reg) {
                    unsigned ub = (unsigned)(baseb[reg] + offb[st]);
                    unsigned short bu = *(const unsigned short*)((const char*)btm_s + ub);
                    float bias = __uint_as_float(((unsigned)bu) << 16);
                    pv[st][reg] = fexp2(sf[st][reg] + bias);
                }
            }
        } else {
            #pragma unroll
            for (int st = 0; st < 4; ++st) {
                bool bad = (k0 + st * 16 + ln) >= N_K;
                #pragma unroll
                for (int reg = 0; reg < 4; ++reg) {
                    unsigned ub = (unsigned)(baseb[reg] + offb[st]);
                    ub = ub > mxb ? mxb : ub;
                    unsigned short bu = *(const unsigned short*)((const char*)btm_s + ub);
                    float bias = __uint_as_float(((unsigned)bu) << 16);
                    pv[st][reg] = bad ? 0.f : fexp2(sf[st][reg] + bias);
                }
            }
        }

        // P -> LDS (per-wave buffer; slot-permuted to match V layout)
        #pragma unroll
        for (int reg = 0; reg < 4; ++reg) {
            uint2 pw = make_uint2(pk_bf16(pv[0][reg], pv[1][reg]),
                                  pk_bf16(pv[2][reg], pv[3][reg]));
            *(uint2*)&P_s[w][g * 4 + reg][4 * ln] = pw;
        }
        __asm__ __volatile__("" ::: "memory");   // order P_s RAW (uint2 write, short8 read)

        // PV + l row-sum (V from LDS)
        #pragma unroll
        for (int kt = 0; kt < 2; ++kt) {
            short8 af = *(const short8*)&P_s[w][ln][g * 8 + kt * 32];
            short8 b0 = *(const short8*)&Vt_s[p][ln][g * 8 + kt * 32];
            short8 b1 = *(const short8*)&Vt_s[p][ln + 16][g * 8 + kt * 32];
            acc0 = __builtin_amdgcn_mfma_f32_16x16x32_bf16(af, b0, acc0, 0, 0, 0);
            acc1 = __builtin_amdgcn_mfma_f32_16x16x32_bf16(af, b1, acc1, 0, 0, 0);
            accL = __builtin_amdgcn_mfma_f32_16x16x32_bf16(af, ones, accL, 0, 0, 0);
        }

        if (notlast) {
            int q2 = p ^ 1;
            *(uint4*)&Vt_s[q2][vrow][vc8] = vreg;
            __syncthreads();
            p = q2;
            vptr += 64;
        }

        // advance key geometry: key += 64 => offb -= 128 B (or 292 B on row wrap)
        #pragma unroll
        for (int st = 0; st < 4; ++st) {
            kcc[st] += 64;
            if (kcc[st] >= 84) { kcc[st] -= 84; offb[st] -= 292; }
            else offb[st] -= 128;
        }
    }

    // accL[reg]: every col holds the same row-sum (C row = A row = q-row g*4+reg)
    const int rbase = (b * 8 + h) * N_Q + q0 + w * 16;
    #pragma unroll
    for (int reg = 0; reg < 4; ++reg) {
        int prow = ks * NROWS + rbase + g * 4 + reg;
        pacc[(size_t)prow * 32 + ln]      = acc0[reg];
        pacc[(size_t)prow * 32 + 16 + ln] = acc1[reg];
        if (ln == 0) pl[prow] = accL[reg];
    }
}

// ---- combine 8 partials + V-BN (folded) + hardswish -> bf16 plane, x4 vectorized.
// Extra 128 blocks (>= 672) convert proj_w -> bf16 into the now-dead q_y region.
__global__ __launch_bounds__(256) void combine_kernel(const float* __restrict__ pl,
                                                      const float* __restrict__ pacc,
                                                      const float* __restrict__ sums_kv,
                                                      const float* __restrict__ kv_g,
                                                      const float* __restrict__ kv_b,
                                                      unsigned short* __restrict__ attn_o,
                                                      const float* __restrict__ proj_w,
                                                      unsigned short* __restrict__ projWb)
{
    if (blockIdx.x >= 672) {   // proj_w fp32 -> bf16 (512*256 = 32768 float4, 128 blocks)
        int i = (blockIdx.x - 672) * 256 + threadIdx.x;
        float4 v = *(const float4*)(proj_w + (size_t)i * 4);
        *(uint2*)(projWb + (size_t)i * 4) = make_uint2(pk_bf16(v.x, v.y), pk_bf16(v.z, v.w));
        return;
    }
    int idx = blockIdx.x * 256 + threadIdx.x;    // NROWS*8 items, 4 channels each
    int r = idx >> 3, e4 = (idx & 7) * 4;
    float L = 0.f;
    float vs[4] = {0.f, 0.f, 0.f, 0.f};
    size_t o = (size_t)r * 32 + e4;
    #pragma unroll
    for (int s2 = 0; s2 < NSPLIT; ++s2) {
        L += pl[(size_t)s2 * NROWS + r];
        float4 vv = *(const float4*)(pacc + (size_t)s2 * NROWS * 32 + o);
        vs[0] += vv.x; vs[1] += vv.y; vs[2] += vv.z; vs[3] += vv.w;
    }
    float invL = 1.f / L;
    int q = r % N_Q;
    int bh = r / N_Q;
    int hh = bh & 7, b = bh >> 3;
    const int ch = hh * 48 + 16 + e4;
    const float invk = 1.f / 10584.f;
    float hs[4];
    #pragma unroll
    for (int u = 0; u < 4; ++u) {
        float v = vs[u];
        float mu  = sums_kv[ch + u] * invk;
        float var = fmaf(-mu, mu, sums_kv[384 + ch + u] * invk);
        float s   = kv_g[ch + u] * rsqrtf(var + 1e-5f);
        float tt  = fmaf(-mu, s, kv_b[ch + u]);
        v = fmaf(s, v * invL, tt);
        hs[u] = v * fminf(fmaxf(v + 3.f, 0.f), 6.f) * (1.f / 6.f);
    }
    *(uint2*)(attn_o + (size_t)(b * N_Q + q) * 256 + hh * 32 + e4) =
        make_uint2(pk_bf16(hs[0], hs[1]), pk_bf16(hs[2], hs[3]));
}

// ---- final BN apply ----
__global__ __launch_bounds__(256) void norm_apply(
    const float* __restrict__ Y, const float* __restrict__ sums,
    const float* __restrict__ g, const float* __restrict__ bb,
    float* __restrict__ out, int rows, int cols, float inv_rows)
{
    __shared__ float sc_s[64], sh_s[64];
    const int t = threadIdx.x;
    const int c0 = blockIdx.x * 64;
    if (t < 64) {
        int c = c0 + t;
        float mu  = sums[c] * inv_rows;
        float var = fmaf(-mu, mu, sums[cols + c] * inv_rows);
        float s   = g[c] * rsqrtf(var + 1e-5f);
        sc_s[t] = s;
        sh_s[t] = fmaf(-mu, s, bb[c]);
    }
    __syncthreads();
    const int c4 = (t & 15) * 4;
    float4 scv = *(const float4*)&sc_s[c4];
    float4 shv = *(const float4*)&sh_s[c4];
    for (int r = blockIdx.y * 16 + (t >> 4); r < rows; r += gridDim.y * 16) {
        size_t off = (size_t)r * cols + c0 + c4;
        float4 v = *(const float4*)(Y + off);
        v.x = fmaf(v.x, scv.x, shv.x);
        v.y = fmaf(v.y, scv.y, shv.y);
        v.z = fmaf(v.z, scv.z, shv.z);
        v.w = fmaf(v.w, scv.w, shv.w);
        *(float4*)(out + off) = v;
    }
}

extern "C" void kernel_launch(void* const* d_in, const int* in_sizes, int n_in,
                              void* d_out, int out_size, void* d_ws, size_t ws_size,
                              hipStream_t stream) {
    (void)n_in; (void)out_size; (void)ws_size;
    const float* x      = (const float*)d_in[0];
    const float* kv_w   = (const float*)d_in[1];
    const float* kv_g   = (const float*)d_in[2];
    const float* kv_b   = (const float*)d_in[3];
    const float* q_w    = (const float*)d_in[4];
    const float* q_g    = (const float*)d_in[5];
    const float* q_b    = (const float*)d_in[6];
    const float* proj_w = (const float*)d_in[7];
    const float* proj_g = (const float*)d_in[8];
    const float* proj_b = (const float*)d_in[9];
    const float* bias_table = (const float*)d_in[10];
    const int*   bias_idxs  = (const int*)d_in[11];
    const int    n_off = in_sizes[10] / 8;
    float* out = (float*)d_out;

    float* ws = (float*)d_ws;
    float* q_y  = ws;                                       // 344,064 f
    float* pacc = q_y + 2688 * 128;                         // 8*NROWS*32 = 5,505,024 f
    float* proj_y = pacc;
    float* pl = pacc + (size_t)NSPLIT * NROWS * 32;         // 8*NROWS = 172,032 f
    unsigned short* attn_o = (unsigned short*)(pl + (size_t)NSPLIT * NROWS);  // 688,128 u16
    unsigned short* Kp  = attn_o + 2688 * 256;              // 2*8*5292*16 u16
    unsigned short* Vpt = Kp + 2 * 8 * N_K * 16;            // 2*8*32*N_KP u16
    float* sums_kv = (float*)(Vpt + 2 * 8 * 32 * N_KP);     // 768
    float* sums_q  = sums_kv + 768;                         // 256
    float* sums_p  = sums_q + 256;                          // 1024  (2048 f contiguous)
    float* bt_r    = sums_p + 1024;                         // 8*5292

    // bf16 staging planes:
    //  Xb/kvWb/qWb overlay pacc  (consumed by gemm_qkv BEFORE attn_mfma clobbers pacc)
    //  projWb overlays q_y       (written by combine_kernel AFTER attn_mfma's last q_y read)
    unsigned short* Xb     = (unsigned short*)pacc;         // 10584*256 u16
    unsigned short* kvWb   = Xb + 10584 * 256;              // 384*256
    unsigned short* qWb    = kvWb + 384 * 256;              // 128*256
    unsigned short* projWb = (unsigned short*)q_y;          // 512*256 u16

    // 1) one-shot fp32 -> bf16 conversion of X + kv/q weights; tail block zeroes stats
    prep_bf16<<<2775, 256, 0, stream>>>(x, kv_w, q_w, Xb, sums_kv);
    // 2) kv + q GEMMs (B-once-in-LDS, A-direct, barrier-free) + prep tails
    gemm_qkv<<<1104 + 168 + 166, 256, 0, stream>>>(Xb, kvWb, qWb, bias_table, bias_idxs,
                                                   n_off, Kp, Vpt, bt_r,
                                                   q_y, sums_kv, sums_q);
    // 3) flash attention: 8-way K split, K-direct (L2), V LDS-dbuf
    attn_mfma<<<2688, 256, 0, stream>>>(Kp, Vpt, q_y, sums_q, q_g, q_b,
                                        sums_kv, kv_g, bt_r, pl, pacc);
    // 4) combine 8 partials + V-BN + hardswish -> bf16; tail converts proj_w -> bf16
    combine_kernel<<<672 + 128, 256, 0, stream>>>(pl, pacc, sums_kv, kv_g, kv_b, attn_o,
                                                  proj_w, projWb);
    // 5) proj GEMM (B-once-in-LDS, A-direct)
    gemm_proj<<<384, 256, 0, stream>>>(attn_o, projWb, proj_y, sums_p);
    // 6) final BN -> out
    norm_apply<<<dim3(8, 84), 256, 0, stream>>>(proj_y, sums_p, proj_g, proj_b, out,
                                                2688, 512, 1.f / 2688.f);
}

// Round 11
// 193.440 us; speedup vs baseline: 1.4491x; 1.0899x over previous
//
#include <hip/hip_runtime.h>
#include <hip/hip_bf16.h>
#include <math.h>

#define N_K 5292
#define N_KP 5376     // N_K padded to multiple of 64 for permuted V layout
#define N_Q 1344
#define NH_KD 128
#define NROWS 21504   // 2*8*1344 (b,h,q) rows of partials
#define NSPLIT 8      // K-splits per (b,h) plane
#define LOG2E 1.4426950408889634f
#define MSTAT 16.0f   // static softmax shift (log2 domain), in QK MFMA C-operand

typedef float f32x4 __attribute__((ext_vector_type(4)));
typedef short short8 __attribute__((ext_vector_type(8)));

__device__ __forceinline__ float fexp2(float x) {
#if __has_builtin(__builtin_amdgcn_exp2f)
    return __builtin_amdgcn_exp2f(x);
#else
    return exp2f(x);
#endif
}

// packed f32x2 -> bf16x2 (v_cvt_pk_bf16_f32); a in low 16 bits
__device__ __forceinline__ unsigned pk_bf16(float a, float b) {
    union { __hip_bfloat162 h; unsigned u; } c;
    c.h = __float22bfloat162_rn(make_float2(a, b));
    return c.u;
}
__device__ __forceinline__ unsigned short f2bf(float a) {
    return (unsigned short)pk_bf16(a, 0.f);
}

// ---- one-shot fp32 -> bf16 conversion of X, kv_w, q_w  (+ stats zero tail block) ----
__global__ __launch_bounds__(256) void prep_bf16(
    const float* __restrict__ X, const float* __restrict__ kv_w,
    const float* __restrict__ q_w,
    unsigned short* __restrict__ Xb, float* __restrict__ sums)
{
    int i = blockIdx.x * 256 + threadIdx.x;   // float4 index into concatenated space
    if (i >= 710144) {                        // stats zero: 256 threads x 8 floats = 2048
        int j = i - 710144;
        float4 z = make_float4(0.f, 0.f, 0.f, 0.f);
        *(float4*)(sums + (size_t)j * 8)     = z;
        *(float4*)(sums + (size_t)j * 8 + 4) = z;
        return;
    }
    const float* src;
    long off;
    if (i < 677376)       { src = X;      off = i; }
    else if (i < 701952)  { src = kv_w;   off = i - 677376; }
    else                  { src = q_w;    off = i - 701952; }
    float4 v = *(const float4*)(src + off * 4);
    *(uint2*)(Xb + (size_t)i * 4) = make_uint2(pk_bf16(v.x, v.y), pk_bf16(v.z, v.w));
}

// ---- GEMM 64x64 tile body: B panel staged ONCE in LDS, A fragments read
// directly from global (each A element is used by exactly one lane -> LDS
// round-trip for A was pure overhead). Barrier-free k-loop. (R9-measured keep.)
__device__ __forceinline__ void gemm_body_direct(
    const unsigned short* __restrict__ A, const unsigned short* __restrict__ W,
    long arow,               // per-LANE A row index (global), or -1 if invalid
    int n0,                  // B panel start row (output column base)
    unsigned short (*Bs)[264], f32x4 acc[4])
{
    const int t = threadIdx.x;
    const int lane = t & 63, g = lane >> 4, ln = lane & 15;

    // stage B panel: 64 rows x 256 cols bf16 = 2048 uint4, 8 per thread
    #pragma unroll
    for (int p = 0; p < 8; ++p) {
        int i = p * 256 + t;                 // uint4 index
        int row = i >> 5, c8 = (i & 31) * 8;
        *(uint4*)&Bs[row][c8] = *(const uint4*)(W + (size_t)(n0 + row) * 256 + c8);
    }
    __syncthreads();

    const unsigned short* aptr =
        (arow >= 0) ? (A + (size_t)arow * 256 + g * 8) : (const unsigned short*)0;

    #pragma unroll
    for (int k0 = 0; k0 < 256; k0 += 32) {
        short8 ah = (short8)0;
        if (aptr) ah = *(const short8*)(aptr + k0);
        #pragma unroll
        for (int nt = 0; nt < 4; ++nt) {
            short8 bh = *(const short8*)&Bs[nt * 16 + ln][k0 + g * 8];
            acc[nt] = __builtin_amdgcn_mfma_f32_16x16x32_bf16(ah, bh, acc[nt], 0, 0, 0);
        }
    }
}

// ---- fused column stats (sum/sumsq of this block's 64 rows) ----
__device__ __forceinline__ void gemm_stats(f32x4 acc[4], float* __restrict__ sums,
                                           int n0, int Ncols, float* scratch)
{
    const int t = threadIdx.x;
    const int w = t >> 6, lane = t & 63, g = lane >> 4, ln = lane & 15;
    float s4[4], q4[4];
    #pragma unroll
    for (int nt = 0; nt < 4; ++nt) {
        float s = acc[nt][0] + acc[nt][1] + acc[nt][2] + acc[nt][3];
        float q = fmaf(acc[nt][0], acc[nt][0], fmaf(acc[nt][1], acc[nt][1],
                  fmaf(acc[nt][2], acc[nt][2], acc[nt][3] * acc[nt][3])));
        s += __shfl_xor(s, 16); s += __shfl_xor(s, 32);
        q += __shfl_xor(q, 16); q += __shfl_xor(q, 32);
        s4[nt] = s; q4[nt] = q;
    }
    __syncthreads();
    float* st_s = scratch;
    float* st_q = scratch + 256;
    if (g == 0) {
        #pragma unroll
        for (int nt = 0; nt < 4; ++nt) {
            st_s[(w * 4 + nt) * 16 + ln] = s4[nt];
            st_q[(w * 4 + nt) * 16 + ln] = q4[nt];
        }
    }
    __syncthreads();
    if (t < 64) {
        int nt = t >> 4, c = t & 15;
        float a = 0.f, b2 = 0.f;
        #pragma unroll
        for (int ww = 0; ww < 4; ++ww) {
            a  += st_s[(ww * 4 + nt) * 16 + c];
            b2 += st_q[(ww * 4 + nt) * 16 + c];
        }
        atomicAdd(&sums[n0 + nt * 16 + c], a);
        atomicAdd(&sums[Ncols + n0 + nt * 16 + c], b2);
    }
}

// ---- kv + q GEMMs + folded prep (race-free Vpt tail zero, bias remap) ----
__global__ __launch_bounds__(256) void gemm_qkv(
    const unsigned short* __restrict__ Xb, const unsigned short* __restrict__ kvWb,
    const unsigned short* __restrict__ qWb,
    const float* __restrict__ bias_table, const int* __restrict__ bias_idxs, int n_off,
    unsigned short* __restrict__ Kp, unsigned short* __restrict__ Vpt,
    float* __restrict__ bt_r,
    float* __restrict__ q_y, float* __restrict__ sums_kv, float* __restrict__ sums_q)
{
    __shared__ unsigned short Bs[64][264];   // 33792 B
    const int t = threadIdx.x;
    const int w = t >> 6, lane = t & 63, g = lane >> 4, ln = lane & 15;
    int id = blockIdx.x;

    if (id >= 1104) {
        id -= 1104;
        if (id < 168) {           // zero the 84 never-written Vpt slots per row
            int i = id * 256 + t; // 512 rows x 84 slots = 43008 (exact)
            int row = i / 84, j = i - row * 84;
            int slot;
            if (j < 20) {         // group [5248,5312): slots of keys 5292..5311
                int kap = 44 + j;
                slot = 5248 + (((kap & 15) << 2) | (kap >> 4));
            } else {              // group [5312,5376): fully padding
                slot = 5312 + (j - 20);
            }
            Vpt[(size_t)row * N_KP + slot] = 0;
        } else {                  // bias remap: bt_r[h][dr*84+dc] = bias * log2e
            int i = (id - 168) * 256 + t;
            if (i < 8 * N_K) {
                int h = i / N_K, j = i - h * N_K;
                bt_r[i] = bias_table[h * n_off + bias_idxs[j]] * LOG2E;
            }
        }
        return;
    }

    f32x4 acc[4];
    #pragma unroll
    for (int nt = 0; nt < 4; ++nt) acc[nt] = (f32x4){0.f, 0.f, 0.f, 0.f};

    if (id < 1008) {            // kv: mtiles=166, nblk=6
        const int xcd = id & 7, id8 = id >> 3;
        const int my = xcd + (id8 / 6) * 8, ny = id8 % 6;
        if (my >= 166) return;
        const int m0 = my * 64, n0 = ny * 64;
        int arow0 = m0 + w * 16 + ln;                 // this lane's A row
        long arow = (arow0 < 10584) ? arow0 : -1;
        gemm_body_direct(Xb, kvWb, arow, n0, Bs, acc);

        #pragma unroll
        for (int nt = 0; nt < 4; ++nt) {
            int c = n0 + nt * 16 + ln;
            int hh = c / 48, cc = c - 48 * hh;
            #pragma unroll
            for (int reg = 0; reg < 4; ++reg) {
                int mr = m0 + w * 16 + g * 4 + reg;
                if (mr < 10584) {
                    int bb = mr >= N_K;
                    int key = mr - bb * N_K;
                    unsigned short v16 = f2bf(acc[nt][reg]);
                    if (cc < 16) {
                        Kp[((size_t)(bb * 8 + hh) * N_K + key) * 16 + cc] = v16;
                    } else {
                        int kap = key & 63;
                        int keyp = (key & ~63) | (((kap & 15) << 2) | (kap >> 4));
                        Vpt[((size_t)(bb * 8 + hh) * 32 + cc - 16) * N_KP + keyp] = v16;
                    }
                }
            }
        }
        gemm_stats(acc, sums_kv, n0, 384, (float*)&Bs[0][0]);
    } else {                    // q: mtiles=42, nblk=2 (strided subsample rows)
        id -= 1008;
        const int xcd = id & 7, id8 = id >> 3;
        const int my = xcd + (id8 / 2) * 8, ny = id8 % 2;
        if (my >= 42) return;
        const int m0 = my * 64, n0 = ny * 64;
        int mrow = m0 + w * 16 + ln;                  // this lane's output row
        int bb = mrow / N_Q;
        int i = mrow - bb * N_Q;
        long arow = (long)(bb * N_K + (i / 42) * 168 + (i % 42) * 2);
        gemm_body_direct(Xb, qWb, arow, n0, Bs, acc);

        #pragma unroll
        for (int nt = 0; nt < 4; ++nt)
            #pragma unroll
            for (int reg = 0; reg < 4; ++reg) {
                int mr = m0 + w * 16 + g * 4 + reg;
                q_y[(size_t)mr * 128 + n0 + nt * 16 + ln] = acc[nt][reg];
            }
        gemm_stats(acc, sums_q, n0, 128, (float*)&Bs[0][0]);
    }
}

// ---- proj GEMM (A bf16 attn_o direct, W bf16 staged once) ----
__global__ __launch_bounds__(256) void gemm_proj(
    const unsigned short* __restrict__ Ap, const unsigned short* __restrict__ Wp,
    float* __restrict__ Y, float* __restrict__ sums)
{
    __shared__ unsigned short Bs[64][264];
    const int t = threadIdx.x;
    const int w = t >> 6, lane = t & 63, g = lane >> 4, ln = lane & 15;
    const int id = blockIdx.x;
    const int xcd = id & 7, id8 = id >> 3;
    const int my = xcd + (id8 / 8) * 8, ny = id8 % 8;
    if (my >= 42) return;
    const int m0 = my * 64, n0 = ny * 64;

    f32x4 acc[4];
    #pragma unroll
    for (int nt = 0; nt < 4; ++nt) acc[nt] = (f32x4){0.f, 0.f, 0.f, 0.f};
    gemm_body_direct(Ap, Wp, (long)(m0 + w * 16 + ln), n0, Bs, acc);

    #pragma unroll
    for (int nt = 0; nt < 4; ++nt)
        #pragma unroll
        for (int reg = 0; reg < 4; ++reg) {
            int mr = m0 + w * 16 + g * 4 + reg;
            Y[(size_t)mr * 512 + n0 + nt * 16 + ln] = acc[nt][reg];
        }
    gemm_stats(acc, sums, n0, 512, (float*)&Bs[0][0]);
}

// ---- MFMA flash attention: 8-way K split; V staged in LDS (dbuf, coalesced),
// K read DIRECT from global (coalesced, L2-resident, XCD-pinned via h=id&7).
// LDS 23080 B. launch_bounds(256,5): VGPR cap ~51 >= the ~48 needed (NO spill;
// empirical cap law on this toolchain is ~256/w — w=6 caused 51MB scratch, R10).
// grid 2688: h=id&7, z=(id>>3)&15 (b*8+ks), qt=id>>7.
__global__ __launch_bounds__(256, 5) void attn_mfma(
    const unsigned short* __restrict__ Kp, const unsigned short* __restrict__ Vpt,
    const float* __restrict__ q_y, const float* __restrict__ sums_q,
    const float* __restrict__ q_g, const float* __restrict__ q_b,
    const float* __restrict__ sums_kv, const float* __restrict__ kv_g,
    const float* __restrict__ bt_r,
    float* __restrict__ pl, float* __restrict__ pacc)
{
    const int id = blockIdx.x;
    const int h = id & 7;
    const int z = (id >> 3) & 15;
    const int qt = id >> 7;
    const int b = z >> 3, ks = z & 7;
    const int t = threadIdx.x;
    const int w = t >> 6, lane = t & 63, g = lane >> 4, ln = lane & 15;

    __shared__ unsigned short btm_s[14 * 166]; // 4648 B mirrored bias (bf16)
    __shared__ unsigned short Vt_s[2][32][72]; // 9216 B (dbuf, b128-read free)
    __shared__ unsigned short P_s[4][16][72];  // 9216 B (per wave)

    const int q0 = qt * 64;
    // tile-quantized split: 83 total tiles, split ks gets tiles [t0, t1)
    const int t0 = (ks * 83) >> 3;
    const int t1 = ((ks + 1) * 83) >> 3;
    const int kstart = t0 * 64;
    const int kend0 = t1 * 64;
    const int kend = kend0 < N_K ? kend0 : N_K;
    const int ntiles = t1 - t0;
    const bool tail = (ks == 7);

    // mirrored-window extents: d_r = rq2 - kr ranges [dmin_r, ...]; rows <= 14
    const int kr0 = kstart / 84;
    const int kr1 = (kend - 1) / 84;
    const int rq2min = (q0 / 42) * 2;
    const int rq2max = ((q0 + 63) / 42) * 2;
    const int dmin_r = rq2min - kr1;
    const int rows = (rq2max - kr0) - dmin_r + 1;    // <= 14
    const int nb = rows * 166;
    const unsigned mxb = (unsigned)((nb - 1) * 2);   // byte clamp (tail-last tile only)
    {   // stage mirrored bf16 bias: btm[j*166+i] = bf16(bt[|dmin_r+j|*84 + |i-83|])
        const float* src = bt_r + h * N_K;
        for (int j = t; j < nb; j += 256) {
            int rr = j / 166, ii = j - rr * 166;
            int dr = dmin_r + rr; dr = dr < 0 ? -dr : dr;
            int dc = ii - 83; dc = dc < 0 ? -dc : dc;
            btm_s[j] = f2bf(src[dr * 84 + dc]);
        }
    }

    // Q A-fragment: q-BN (0.25*log2e folded) times K-channel BN scale
    short8 qfrag = (short8)0;
    if (lane < 32) {
        const float invq = 1.f / 2688.f, invk = 1.f / 10584.f;
        const float post = 0.25f * LOG2E;
        const int c0 = h * 16 + g * 8;
        const int ck = h * 48 + g * 8;
        const float* qp = q_y + (size_t)(b * N_Q + q0 + w * 16 + ln) * NH_KD + c0;
        float vv[8];
        #pragma unroll
        for (int j = 0; j < 8; ++j) {
            float mu  = sums_q[c0 + j] * invq;
            float var = fmaf(-mu, mu, sums_q[128 + c0 + j] * invq);
            float s   = q_g[c0 + j] * rsqrtf(var + 1e-5f) * post;
            float vq  = fmaf(qp[j], s, fmaf(-mu, s, q_b[c0 + j] * post));
            float muk = sums_kv[ck + j] * invk;
            float vrk = fmaf(-muk, muk, sums_kv[384 + ck + j] * invk);
            float sk  = kv_g[ck + j] * rsqrtf(vrk + 1e-5f);
            vv[j] = vq * sk;
        }
        union { short8 s; unsigned u[4]; } qf;
        qf.u[0] = pk_bf16(vv[0], vv[1]); qf.u[1] = pk_bf16(vv[2], vv[3]);
        qf.u[2] = pk_bf16(vv[4], vv[5]); qf.u[3] = pk_bf16(vv[6], vv[7]);
        qfrag = qf.s;
    }

    // all-ones bf16 B-fragment (for MFMA row-sum of P -> l)
    union { short8 s; unsigned u[4]; } onef;
    #pragma unroll
    for (int j = 0; j < 4; ++j) onef.u[j] = 0x3F803F80u;
    const short8 ones = onef.s;

    // per-reg base BYTE offset into mirrored bf16 table (constant over key loop)
    int baseb[4];
    #pragma unroll
    for (int reg = 0; reg < 4; ++reg) {
        int qg = q0 + w * 16 + g * 4 + reg;
        int rq2 = (qg / 42) * 2;
        int cq2 = (qg % 42) * 2;
        baseb[reg] = ((rq2 - dmin_r) * 166 + cq2 + 83) * 2;
    }
    // per-subtile BYTE offset, advanced incrementally: off = -(kr*166 + kc)*2
    int offb[4], kcc[4];
    #pragma unroll
    for (int st = 0; st < 4; ++st) {
        int kg = kstart + st * 16 + ln;
        int okr = kg / 84;
        kcc[st] = kg - okr * 84;
        offb[st] = -(okr * 166 + kcc[st]) * 2;
    }

    // K: direct-global fragment pointer (coalesced 32B/key, L2-resident)
    const unsigned short* kp_u16 = Kp + (size_t)(b * 8 + h) * N_K * 16;
    // V: LDS-staged (coalesced b128 stage; per-lane strided access stays in LDS)
    const int vrow = t >> 3, vc8 = (t & 7) * 8;
    const unsigned short* vptr = Vpt + (size_t)(b * 8 + h) * 32 * N_KP
                                     + (size_t)vrow * N_KP + kstart + vc8;

    uint4 vreg = *(const uint4*)vptr;
    *(uint4*)&Vt_s[0][vrow][vc8] = vreg;
    __syncthreads();   // V(0) + bias table ready

    f32x4 acc0 = {0.f, 0.f, 0.f, 0.f}, acc1 = {0.f, 0.f, 0.f, 0.f};
    f32x4 accL = {0.f, 0.f, 0.f, 0.f};              // l via MFMA(P, ones)
    const f32x4 minit = {-MSTAT, -MSTAT, -MSTAT, -MSTAT};  // static shift via C operand
    int p = 0;

    for (int it = 0; it < ntiles; ++it) {
        const int k0 = kstart + it * 64;
        const bool notlast = (it + 1 < ntiles);
        if (notlast) vreg = *(const uint4*)(vptr + 64);   // next V tile, issued early

        // QK^T: K fragments straight from global (st: 16 keys x 32B, coalesced)
        f32x4 sf[4];
        #pragma unroll
        for (int st = 0; st < 4; ++st) {
            short8 bf = (short8)0;
            if (lane < 32) {
                int key = k0 + st * 16 + ln;
                key = key > N_K - 1 ? N_K - 1 : key;
                bf = *(const short8*)(kp_u16 + (size_t)key * 16 + g * 8);
            }
            sf[st] = __builtin_amdgcn_mfma_f32_16x16x32_bf16(qfrag, bf, minit, 0, 0, 0);
        }

        // p = exp2(qk - MSTAT + bias). Clamp+mask only in the last tile of tail
        // (ks==7) blocks; all other indices provably in-window.
        float pv[4][4];
        const bool clampit = tail && (it == ntiles - 1);
        if (!clampit) {
            #pragma unroll
            for (int st = 0; st < 4; ++st) {
                #pragma unroll
                for (int reg = 0; reg < 4; ++reg) {
                    unsigned ub = (unsigned)(baseb[reg] + offb[st]);
                    unsigned short bu = *(const unsigned short*)((const char*)btm_s + ub);
                    float bias = __uint_as_float(((unsigned)bu) << 16);
                    pv[st][reg] = fexp2(sf[st][reg] + bias);
                }
            }
        } else {
            #pragma unroll
            for (int st = 0; st < 4; ++st) {
                bool bad = (k0 + st * 16 + ln) >= N_K;
                #pragma unroll
                for (int reg = 0; reg < 4; ++reg) {
                    unsigned ub = (unsigned)(baseb[reg] + offb[st]);
                    ub = ub > mxb ? mxb : ub;
                    unsigned short bu = *(const unsigned short*)((const char*)btm_s + ub);
                    float bias = __uint_as_float(((unsigned)bu) << 16);
                    pv[st][reg] = bad ? 0.f : fexp2(sf[st][reg] + bias);
                }
            }
        }

        // P -> LDS (per-wave buffer; slot-permuted to match V layout)
        #pragma unroll
        for (int reg = 0; reg < 4; ++reg) {
            uint2 pw = make_uint2(pk_bf16(pv[0][reg], pv[1][reg]),
                                  pk_bf16(pv[2][reg], pv[3][reg]));
            *(uint2*)&P_s[w][g * 4 + reg][4 * ln] = pw;
        }
        __asm__ __volatile__("" ::: "memory");   // order P_s RAW (uint2 write, short8 read)

        // PV + l row-sum (V from LDS)
        #pragma unroll
        for (int kt = 0; kt < 2; ++kt) {
            short8 af = *(const short8*)&P_s[w][ln][g * 8 + kt * 32];
            short8 b0 = *(const short8*)&Vt_s[p][ln][g * 8 + kt * 32];
            short8 b1 = *(const short8*)&Vt_s[p][ln + 16][g * 8 + kt * 32];
            acc0 = __builtin_amdgcn_mfma_f32_16x16x32_bf16(af, b0, acc0, 0, 0, 0);
            acc1 = __builtin_amdgcn_mfma_f32_16x16x32_bf16(af, b1, acc1, 0, 0, 0);
            accL = __builtin_amdgcn_mfma_f32_16x16x32_bf16(af, ones, accL, 0, 0, 0);
        }

        if (notlast) {
            int q2 = p ^ 1;
            *(uint4*)&Vt_s[q2][vrow][vc8] = vreg;
            __syncthreads();
            p = q2;
            vptr += 64;
        }

        // advance key geometry: key += 64 => offb -= 128 B (or 292 B on row wrap)
        #pragma unroll
        for (int st = 0; st < 4; ++st) {
            kcc[st] += 64;
            if (kcc[st] >= 84) { kcc[st] -= 84; offb[st] -= 292; }
            else offb[st] -= 128;
        }
    }

    // accL[reg]: every col holds the same row-sum (C row = A row = q-row g*4+reg)
    const int rbase = (b * 8 + h) * N_Q + q0 + w * 16;
    #pragma unroll
    for (int reg = 0; reg < 4; ++reg) {
        int prow = ks * NROWS + rbase + g * 4 + reg;
        pacc[(size_t)prow * 32 + ln]      = acc0[reg];
        pacc[(size_t)prow * 32 + 16 + ln] = acc1[reg];
        if (ln == 0) pl[prow] = accL[reg];
    }
}

// ---- combine 8 partials + V-BN (folded) + hardswish -> bf16 plane, x4 vectorized.
// Extra 128 blocks (>= 672) convert proj_w -> bf16 into the now-dead q_y region.
__global__ __launch_bounds__(256) void combine_kernel(const float* __restrict__ pl,
                                                      const float* __restrict__ pacc,
                                                      const float* __restrict__ sums_kv,
                                                      const float* __restrict__ kv_g,
                                                      const float* __restrict__ kv_b,
                                                      unsigned short* __restrict__ attn_o,
                                                      const float* __restrict__ proj_w,
                                                      unsigned short* __restrict__ projWb)
{
    if (blockIdx.x >= 672) {   // proj_w fp32 -> bf16 (512*256 = 32768 float4, 128 blocks)
        int i = (blockIdx.x - 672) * 256 + threadIdx.x;
        float4 v = *(const float4*)(proj_w + (size_t)i * 4);
        *(uint2*)(projWb + (size_t)i * 4) = make_uint2(pk_bf16(v.x, v.y), pk_bf16(v.z, v.w));
        return;
    }
    int idx = blockIdx.x * 256 + threadIdx.x;    // NROWS*8 items, 4 channels each
    int r = idx >> 3, e4 = (idx & 7) * 4;
    float L = 0.f;
    float vs[4] = {0.f, 0.f, 0.f, 0.f};
    size_t o = (size_t)r * 32 + e4;
    #pragma unroll
    for (int s2 = 0; s2 < NSPLIT; ++s2) {
        L += pl[(size_t)s2 * NROWS + r];
        float4 vv = *(const float4*)(pacc + (size_t)s2 * NROWS * 32 + o);
        vs[0] += vv.x; vs[1] += vv.y; vs[2] += vv.z; vs[3] += vv.w;
    }
    float invL = 1.f / L;
    int q = r % N_Q;
    int bh = r / N_Q;
    int hh = bh & 7, b = bh >> 3;
    const int ch = hh * 48 + 16 + e4;
    const float invk = 1.f / 10584.f;
    float hs[4];
    #pragma unroll
    for (int u = 0; u < 4; ++u) {
        float v = vs[u];
        float mu  = sums_kv[ch + u] * invk;
        float var = fmaf(-mu, mu, sums_kv[384 + ch + u] * invk);
        float s   = kv_g[ch + u] * rsqrtf(var + 1e-5f);
        float tt  = fmaf(-mu, s, kv_b[ch + u]);
        v = fmaf(s, v * invL, tt);
        hs[u] = v * fminf(fmaxf(v + 3.f, 0.f), 6.f) * (1.f / 6.f);
    }
    *(uint2*)(attn_o + (size_t)(b * N_Q + q) * 256 + hh * 32 + e4) =
        make_uint2(pk_bf16(hs[0], hs[1]), pk_bf16(hs[2], hs[3]));
}

// ---- final BN apply ----
__global__ __launch_bounds__(256) void norm_apply(
    const float* __restrict__ Y, const float* __restrict__ sums,
    const float* __restrict__ g, const float* __restrict__ bb,
    float* __restrict__ out, int rows, int cols, float inv_rows)
{
    __shared__ float sc_s[64], sh_s[64];
    const int t = threadIdx.x;
    const int c0 = blockIdx.x * 64;
    if (t < 64) {
        int c = c0 + t;
        float mu  = sums[c] * inv_rows;
        float var = fmaf(-mu, mu, sums[cols + c] * inv_rows);
        float s   = g[c] * rsqrtf(var + 1e-5f);
        sc_s[t] = s;
        sh_s[t] = fmaf(-mu, s, bb[c]);
    }
    __syncthreads();
    const int c4 = (t & 15) * 4;
    float4 scv = *(const float4*)&sc_s[c4];
    float4 shv = *(const float4*)&sh_s[c4];
    for (int r = blockIdx.y * 16 + (t >> 4); r < rows; r += gridDim.y * 16) {
        size_t off = (size_t)r * cols + c0 + c4;
        float4 v = *(const float4*)(Y + off);
        v.x = fmaf(v.x, scv.x, shv.x);
        v.y = fmaf(v.y, scv.y, shv.y);
        v.z = fmaf(v.z, scv.z, shv.z);
        v.w = fmaf(v.w, scv.w, shv.w);
        *(float4*)(out + off) = v;
    }
}

extern "C" void kernel_launch(void* const* d_in, const int* in_sizes, int n_in,
                              void* d_out, int out_size, void* d_ws, size_t ws_size,
                              hipStream_t stream) {
    (void)n_in; (void)out_size; (void)ws_size;
    const float* x      = (const float*)d_in[0];
    const float* kv_w   = (const float*)d_in[1];
    const float* kv_g   = (const float*)d_in[2];
    const float* kv_b   = (const float*)d_in[3];
    const float* q_w    = (const float*)d_in[4];
    const float* q_g    = (const float*)d_in[5];
    const float* q_b    = (const float*)d_in[6];
    const float* proj_w = (const float*)d_in[7];
    const float* proj_g = (const float*)d_in[8];
    const float* proj_b = (const float*)d_in[9];
    const float* bias_table = (const float*)d_in[10];
    const int*   bias_idxs  = (const int*)d_in[11];
    const int    n_off = in_sizes[10] / 8;
    float* out = (float*)d_out;

    float* ws = (float*)d_ws;
    float* q_y  = ws;                                       // 344,064 f
    float* pacc = q_y + 2688 * 128;                         // 8*NROWS*32 = 5,505,024 f
    float* proj_y = pacc;
    float* pl = pacc + (size_t)NSPLIT * NROWS * 32;         // 8*NROWS = 172,032 f
    unsigned short* attn_o = (unsigned short*)(pl + (size_t)NSPLIT * NROWS);  // 688,128 u16
    unsigned short* Kp  = attn_o + 2688 * 256;              // 2*8*5292*16 u16
    unsigned short* Vpt = Kp + 2 * 8 * N_K * 16;            // 2*8*32*N_KP u16
    float* sums_kv = (float*)(Vpt + 2 * 8 * 32 * N_KP);     // 768
    float* sums_q  = sums_kv + 768;                         // 256
    float* sums_p  = sums_q + 256;                          // 1024  (2048 f contiguous)
    float* bt_r    = sums_p + 1024;                         // 8*5292

    // bf16 staging planes:
    //  Xb/kvWb/qWb overlay pacc  (consumed by gemm_qkv BEFORE attn_mfma clobbers pacc)
    //  projWb overlays q_y       (written by combine_kernel AFTER attn_mfma's last q_y read)
    unsigned short* Xb     = (unsigned short*)pacc;         // 10584*256 u16
    unsigned short* kvWb   = Xb + 10584 * 256;              // 384*256
    unsigned short* qWb    = kvWb + 384 * 256;              // 128*256
    unsigned short* projWb = (unsigned short*)q_y;          // 512*256 u16

    // 1) one-shot fp32 -> bf16 conversion of X + kv/q weights; tail block zeroes stats
    prep_bf16<<<2775, 256, 0, stream>>>(x, kv_w, q_w, Xb, sums_kv);
    // 2) kv + q GEMMs (B-once-in-LDS, A-direct, barrier-free) + prep tails
    gemm_qkv<<<1104 + 168 + 166, 256, 0, stream>>>(Xb, kvWb, qWb, bias_table, bias_idxs,
                                                   n_off, Kp, Vpt, bt_r,
                                                   q_y, sums_kv, sums_q);
    // 3) flash attention: 8-way K split, K-direct (L2), V LDS-dbuf, no-spill bounds
    attn_mfma<<<2688, 256, 0, stream>>>(Kp, Vpt, q_y, sums_q, q_g, q_b,
                                        sums_kv, kv_g, bt_r, pl, pacc);
    // 4) combine 8 partials + V-BN + hardswish -> bf16; tail converts proj_w -> bf16
    combine_kernel<<<672 + 128, 256, 0, stream>>>(pl, pacc, sums_kv, kv_g, kv_b, attn_o,
                                                  proj_w, projWb);
    // 5) proj GEMM (B-once-in-LDS, A-direct)
    gemm_proj<<<384, 256, 0, stream>>>(attn_o, projWb, proj_y, sums_p);
    // 6) final BN -> out
    norm_apply<<<dim3(8, 84), 256, 0, stream>>>(proj_y, sums_p, proj_g, proj_b, out,
                                                2688, 512, 1.f / 2688.f);
}

// Round 12
// 180.689 us; speedup vs baseline: 1.5514x; 1.0706x over previous
//
#include <hip/hip_runtime.h>
#include <hip/hip_bf16.h>
#include <math.h>

#define N_K 5292
#define N_KP 5376     // N_K padded to multiple of 64 for permuted V layout
#define N_Q 1344
#define NH_KD 128
#define NROWS 21504   // 2*8*1344 (b,h,q) rows of partials
#define NSPLIT 8      // K-splits per (b,h) plane
#define LOG2E 1.4426950408889634f
#define MSTAT 16.0f   // static softmax shift (log2 domain), folded into bt_r

typedef float f32x4 __attribute__((ext_vector_type(4)));
typedef short short8 __attribute__((ext_vector_type(8)));

__device__ __forceinline__ float fexp2(float x) {
#if __has_builtin(__builtin_amdgcn_exp2f)
    return __builtin_amdgcn_exp2f(x);
#else
    return exp2f(x);
#endif
}

// packed f32x2 -> bf16x2 (v_cvt_pk_bf16_f32); a in low 16 bits
__device__ __forceinline__ unsigned pk_bf16(float a, float b) {
    union { __hip_bfloat162 h; unsigned u; } c;
    c.h = __float22bfloat162_rn(make_float2(a, b));
    return c.u;
}
__device__ __forceinline__ unsigned short f2bf(float a) {
    return (unsigned short)pk_bf16(a, 0.f);
}

// ---- one-shot fp32 -> bf16 conversion of X, kv_w, q_w  (+ stats zero tail block) ----
__global__ __launch_bounds__(256) void prep_bf16(
    const float* __restrict__ X, const float* __restrict__ kv_w,
    const float* __restrict__ q_w,
    unsigned short* __restrict__ Xb, float* __restrict__ sums)
{
    int i = blockIdx.x * 256 + threadIdx.x;   // float4 index into concatenated space
    if (i >= 710144) {                        // stats zero: 256 threads x 8 floats = 2048
        int j = i - 710144;
        float4 z = make_float4(0.f, 0.f, 0.f, 0.f);
        *(float4*)(sums + (size_t)j * 8)     = z;
        *(float4*)(sums + (size_t)j * 8 + 4) = z;
        return;
    }
    const float* src;
    long off;
    if (i < 677376)       { src = X;      off = i; }
    else if (i < 701952)  { src = kv_w;   off = i - 677376; }
    else                  { src = q_w;    off = i - 701952; }
    float4 v = *(const float4*)(src + off * 4);
    *(uint2*)(Xb + (size_t)i * 4) = make_uint2(pk_bf16(v.x, v.y), pk_bf16(v.z, v.w));
}

// ---- GEMM 64x64 tile body: B panel staged ONCE in LDS, A fragments direct ----
__device__ __forceinline__ void gemm_body_direct(
    const unsigned short* __restrict__ A, const unsigned short* __restrict__ W,
    long arow, int n0,
    unsigned short (*Bs)[264], f32x4 acc[4])
{
    const int t = threadIdx.x;
    const int lane = t & 63, g = lane >> 4, ln = lane & 15;

    #pragma unroll
    for (int p = 0; p < 8; ++p) {
        int i = p * 256 + t;                 // uint4 index
        int row = i >> 5, c8 = (i & 31) * 8;
        *(uint4*)&Bs[row][c8] = *(const uint4*)(W + (size_t)(n0 + row) * 256 + c8);
    }
    __syncthreads();

    const unsigned short* aptr =
        (arow >= 0) ? (A + (size_t)arow * 256 + g * 8) : (const unsigned short*)0;

    #pragma unroll
    for (int k0 = 0; k0 < 256; k0 += 32) {
        short8 ah = (short8)0;
        if (aptr) ah = *(const short8*)(aptr + k0);
        #pragma unroll
        for (int nt = 0; nt < 4; ++nt) {
            short8 bh = *(const short8*)&Bs[nt * 16 + ln][k0 + g * 8];
            acc[nt] = __builtin_amdgcn_mfma_f32_16x16x32_bf16(ah, bh, acc[nt], 0, 0, 0);
        }
    }
}

// ---- fused column stats (sum/sumsq of this block's 64 rows) ----
__device__ __forceinline__ void gemm_stats(f32x4 acc[4], float* __restrict__ sums,
                                           int n0, int Ncols, float* scratch)
{
    const int t = threadIdx.x;
    const int w = t >> 6, lane = t & 63, g = lane >> 4, ln = lane & 15;
    float s4[4], q4[4];
    #pragma unroll
    for (int nt = 0; nt < 4; ++nt) {
        float s = acc[nt][0] + acc[nt][1] + acc[nt][2] + acc[nt][3];
        float q = fmaf(acc[nt][0], acc[nt][0], fmaf(acc[nt][1], acc[nt][1],
                  fmaf(acc[nt][2], acc[nt][2], acc[nt][3] * acc[nt][3])));
        s += __shfl_xor(s, 16); s += __shfl_xor(s, 32);
        q += __shfl_xor(q, 16); q += __shfl_xor(q, 32);
        s4[nt] = s; q4[nt] = q;
    }
    __syncthreads();
    float* st_s = scratch;
    float* st_q = scratch + 256;
    if (g == 0) {
        #pragma unroll
        for (int nt = 0; nt < 4; ++nt) {
            st_s[(w * 4 + nt) * 16 + ln] = s4[nt];
            st_q[(w * 4 + nt) * 16 + ln] = q4[nt];
        }
    }
    __syncthreads();
    if (t < 64) {
        int nt = t >> 4, c = t & 15;
        float a = 0.f, b2 = 0.f;
        #pragma unroll
        for (int ww = 0; ww < 4; ++ww) {
            a  += st_s[(ww * 4 + nt) * 16 + c];
            b2 += st_q[(ww * 4 + nt) * 16 + c];
        }
        atomicAdd(&sums[n0 + nt * 16 + c], a);
        atomicAdd(&sums[Ncols + n0 + nt * 16 + c], b2);
    }
}

// ---- kv + q GEMMs + folded prep (race-free Vpt tail zero, bias remap) ----
__global__ __launch_bounds__(256) void gemm_qkv(
    const unsigned short* __restrict__ Xb, const unsigned short* __restrict__ kvWb,
    const unsigned short* __restrict__ qWb,
    const float* __restrict__ bias_table, const int* __restrict__ bias_idxs, int n_off,
    unsigned short* __restrict__ Kp, unsigned short* __restrict__ Vpt,
    float* __restrict__ bt_r,
    float* __restrict__ q_y, float* __restrict__ sums_kv, float* __restrict__ sums_q)
{
    __shared__ unsigned short Bs[64][264];   // 33792 B
    const int t = threadIdx.x;
    const int w = t >> 6, lane = t & 63, g = lane >> 4, ln = lane & 15;
    int id = blockIdx.x;

    if (id >= 1104) {
        id -= 1104;
        if (id < 168) {           // zero the 84 never-written Vpt slots per row
            int i = id * 256 + t; // 512 rows x 84 slots = 43008 (exact)
            int row = i / 84, j = i - row * 84;
            int slot;
            if (j < 20) {         // group [5248,5312): slots of keys 5292..5311
                int kap = 44 + j;
                slot = 5248 + (((kap & 15) << 2) | (kap >> 4));
            } else {              // group [5312,5376): fully padding
                slot = 5312 + (j - 20);
            }
            Vpt[(size_t)row * N_KP + slot] = 0;
        } else {                  // bias remap: bt_r = bias*log2e - MSTAT (C-operand fold)
            int i = (id - 168) * 256 + t;
            if (i < 8 * N_K) {
                int h = i / N_K, j = i - h * N_K;
                bt_r[i] = fmaf(bias_table[h * n_off + bias_idxs[j]], LOG2E, -MSTAT);
            }
        }
        return;
    }

    f32x4 acc[4];
    #pragma unroll
    for (int nt = 0; nt < 4; ++nt) acc[nt] = (f32x4){0.f, 0.f, 0.f, 0.f};

    if (id < 1008) {            // kv: mtiles=166, nblk=6
        const int xcd = id & 7, id8 = id >> 3;
        const int my = xcd + (id8 / 6) * 8, ny = id8 % 6;
        if (my >= 166) return;
        const int m0 = my * 64, n0 = ny * 64;
        int arow0 = m0 + w * 16 + ln;
        long arow = (arow0 < 10584) ? arow0 : -1;
        gemm_body_direct(Xb, kvWb, arow, n0, Bs, acc);

        #pragma unroll
        for (int nt = 0; nt < 4; ++nt) {
            int c = n0 + nt * 16 + ln;
            int hh = c / 48, cc = c - 48 * hh;
            #pragma unroll
            for (int reg = 0; reg < 4; ++reg) {
                int mr = m0 + w * 16 + g * 4 + reg;
                if (mr < 10584) {
                    int bb = mr >= N_K;
                    int key = mr - bb * N_K;
                    unsigned short v16 = f2bf(acc[nt][reg]);
                    if (cc < 16) {
                        Kp[((size_t)(bb * 8 + hh) * N_K + key) * 16 + cc] = v16;
                    } else {
                        int kap = key & 63;
                        int keyp = (key & ~63) | (((kap & 15) << 2) | (kap >> 4));
                        Vpt[((size_t)(bb * 8 + hh) * 32 + cc - 16) * N_KP + keyp] = v16;
                    }
                }
            }
        }
        gemm_stats(acc, sums_kv, n0, 384, (float*)&Bs[0][0]);
    } else {                    // q: mtiles=42, nblk=2 (strided subsample rows)
        id -= 1008;
        const int xcd = id & 7, id8 = id >> 3;
        const int my = xcd + (id8 / 2) * 8, ny = id8 % 2;
        if (my >= 42) return;
        const int m0 = my * 64, n0 = ny * 64;
        int mrow = m0 + w * 16 + ln;
        int bb = mrow / N_Q;
        int i = mrow - bb * N_Q;
        long arow = (long)(bb * N_K + (i / 42) * 168 + (i % 42) * 2);
        gemm_body_direct(Xb, qWb, arow, n0, Bs, acc);

        #pragma unroll
        for (int nt = 0; nt < 4; ++nt)
            #pragma unroll
            for (int reg = 0; reg < 4; ++reg) {
                int mr = m0 + w * 16 + g * 4 + reg;
                q_y[(size_t)mr * 128 + n0 + nt * 16 + ln] = acc[nt][reg];
            }
        gemm_stats(acc, sums_q, n0, 128, (float*)&Bs[0][0]);
    }
}

// ---- proj GEMM (A bf16 attn_o direct, W bf16 staged once) ----
__global__ __launch_bounds__(256) void gemm_proj(
    const unsigned short* __restrict__ Ap, const unsigned short* __restrict__ Wp,
    float* __restrict__ Y, float* __restrict__ sums)
{
    __shared__ unsigned short Bs[64][264];
    const int t = threadIdx.x;
    const int w = t >> 6, lane = t & 63, g = lane >> 4, ln = lane & 15;
    const int id = blockIdx.x;
    const int xcd = id & 7, id8 = id >> 3;
    const int my = xcd + (id8 / 8) * 8, ny = id8 % 8;
    if (my >= 42) return;
    const int m0 = my * 64, n0 = ny * 64;

    f32x4 acc[4];
    #pragma unroll
    for (int nt = 0; nt < 4; ++nt) acc[nt] = (f32x4){0.f, 0.f, 0.f, 0.f};
    gemm_body_direct(Ap, Wp, (long)(m0 + w * 16 + ln), n0, Bs, acc);

    #pragma unroll
    for (int nt = 0; nt < 4; ++nt)
        #pragma unroll
        for (int reg = 0; reg < 4; ++reg) {
            int mr = m0 + w * 16 + g * 4 + reg;
            Y[(size_t)mr * 512 + n0 + nt * 16 + ln] = acc[nt][reg];
        }
    gemm_stats(acc, sums, n0, 512, (float*)&Bs[0][0]);
}

// ---- MFMA flash attention: 8-way K split; bias delivered via MFMA C-operand
// (f32 LDS table, -MSTAT pre-folded -> no lshl/add per element); K fragments
// prefetched one tile ahead from global into registers (latency hidden under
// the previous tile's exp/PV); V LDS-dbuf. LDS 27728 B -> 5 blocks/CU.
// grid 2688: h=id&7, z=(id>>3)&15 (b*8+ks), qt=id>>7.
__global__ __launch_bounds__(256, 4) void attn_mfma(
    const unsigned short* __restrict__ Kp, const unsigned short* __restrict__ Vpt,
    const float* __restrict__ q_y, const float* __restrict__ sums_q,
    const float* __restrict__ q_g, const float* __restrict__ q_b,
    const float* __restrict__ sums_kv, const float* __restrict__ kv_g,
    const float* __restrict__ bt_r,
    float* __restrict__ pl, float* __restrict__ pacc)
{
    const int id = blockIdx.x;
    const int h = id & 7;
    const int z = (id >> 3) & 15;
    const int qt = id >> 7;
    const int b = z >> 3, ks = z & 7;
    const int t = threadIdx.x;
    const int w = t >> 6, lane = t & 63, g = lane >> 4, ln = lane & 15;

    __shared__ float btm_s[14 * 166];          // 9296 B mirrored bias (f32, -MSTAT folded)
    __shared__ unsigned short Vt_s[2][32][72]; // 9216 B (dbuf, b128-read free)
    __shared__ unsigned short P_s[4][16][72];  // 9216 B (per wave)

    const int q0 = qt * 64;
    const int t0 = (ks * 83) >> 3;
    const int t1 = ((ks + 1) * 83) >> 3;
    const int kstart = t0 * 64;
    const int kend0 = t1 * 64;
    const int kend = kend0 < N_K ? kend0 : N_K;
    const int ntiles = t1 - t0;
    const bool tail = (ks == 7);

    // mirrored-window extents; rows <= 14
    const int kr0 = kstart / 84;
    const int kr1 = (kend - 1) / 84;
    const int rq2min = (q0 / 42) * 2;
    const int rq2max = ((q0 + 63) / 42) * 2;
    const int dmin_r = rq2min - kr1;
    const int rows = (rq2max - kr0) - dmin_r + 1;
    const int nb = rows * 166;
    const unsigned mxb = (unsigned)((nb - 1) * 4);   // byte clamp (tail-last tile only)
    {   // stage mirrored f32 bias: btm[j*166+i] = bt[|dmin_r+j|*84 + |i-83|]
        const float* src = bt_r + h * N_K;
        for (int j = t; j < nb; j += 256) {
            int rr = j / 166, ii = j - rr * 166;
            int dr = dmin_r + rr; dr = dr < 0 ? -dr : dr;
            int dc = ii - 83; dc = dc < 0 ? -dc : dc;
            btm_s[j] = src[dr * 84 + dc];
        }
    }

    // Q A-fragment: q-BN (0.25*log2e folded) times K-channel BN scale
    short8 qfrag = (short8)0;
    if (lane < 32) {
        const float invq = 1.f / 2688.f, invk = 1.f / 10584.f;
        const float post = 0.25f * LOG2E;
        const int c0 = h * 16 + g * 8;
        const int ck = h * 48 + g * 8;
        const float* qp = q_y + (size_t)(b * N_Q + q0 + w * 16 + ln) * NH_KD + c0;
        float vv[8];
        #pragma unroll
        for (int j = 0; j < 8; ++j) {
            float mu  = sums_q[c0 + j] * invq;
            float var = fmaf(-mu, mu, sums_q[128 + c0 + j] * invq);
            float s   = q_g[c0 + j] * rsqrtf(var + 1e-5f) * post;
            float vq  = fmaf(qp[j], s, fmaf(-mu, s, q_b[c0 + j] * post));
            float muk = sums_kv[ck + j] * invk;
            float vrk = fmaf(-muk, muk, sums_kv[384 + ck + j] * invk);
            float sk  = kv_g[ck + j] * rsqrtf(vrk + 1e-5f);
            vv[j] = vq * sk;
        }
        union { short8 s; unsigned u[4]; } qf;
        qf.u[0] = pk_bf16(vv[0], vv[1]); qf.u[1] = pk_bf16(vv[2], vv[3]);
        qf.u[2] = pk_bf16(vv[4], vv[5]); qf.u[3] = pk_bf16(vv[6], vv[7]);
        qfrag = qf.s;
    }

    // all-ones bf16 B-fragment (for MFMA row-sum of P -> l)
    union { short8 s; unsigned u[4]; } onef;
    #pragma unroll
    for (int j = 0; j < 4; ++j) onef.u[j] = 0x3F803F80u;
    const short8 ones = onef.s;

    // per-reg base BYTE offset into mirrored f32 table (constant over key loop)
    int baseb[4];
    #pragma unroll
    for (int reg = 0; reg < 4; ++reg) {
        int qg = q0 + w * 16 + g * 4 + reg;
        int rq2 = (qg / 42) * 2;
        int cq2 = (qg % 42) * 2;
        baseb[reg] = ((rq2 - dmin_r) * 166 + cq2 + 83) * 4;
    }
    // per-subtile BYTE offset, advanced incrementally: off = -(kr*166 + kc)*4
    int offb[4], kcc[4];
    #pragma unroll
    for (int st = 0; st < 4; ++st) {
        int kg = kstart + st * 16 + ln;
        int okr = kg / 84;
        kcc[st] = kg - okr * 84;
        offb[st] = -(okr * 166 + kcc[st]) * 4;
    }

    // K: rolling direct-global byte pointer. lanes>=32 read overlapping (finite)
    // neighbor data; their products are exactly 0 since qfrag==0 there.
    const char* kb = (const char*)(Kp + (size_t)(b * 8 + h) * N_K * 16)
                   + (size_t)kstart * 32 + ln * 32 + g * 16;
    short8 kC0, kC1, kC2, kC3, kN0, kN1, kN2, kN3;
    kC0 = *(const short8*)(kb);
    kC1 = *(const short8*)(kb + 512);
    kC2 = *(const short8*)(kb + 1024);
    kC3 = *(const short8*)(kb + 1536);
    kb += 2048;

    // V: LDS-staged dbuf (coalesced b128 stage)
    const int vrow = t >> 3, vc8 = (t & 7) * 8;
    const unsigned short* vptr = Vpt + (size_t)(b * 8 + h) * 32 * N_KP
                                     + (size_t)vrow * N_KP + kstart + vc8;
    uint4 vreg = *(const uint4*)vptr;
    *(uint4*)&Vt_s[0][vrow][vc8] = vreg;
    __syncthreads();   // V(0) + bias table ready

    f32x4 acc0 = {0.f, 0.f, 0.f, 0.f}, acc1 = {0.f, 0.f, 0.f, 0.f};
    f32x4 accL = {0.f, 0.f, 0.f, 0.f};              // l via MFMA(P, ones)
    int p = 0;

    for (int it = 0; it < ntiles; ++it) {
        const int k0 = kstart + it * 64;
        const bool notlast = (it + 1 < ntiles);
        if (notlast) {   // issue next-tile loads early (latency hides under exp/PV)
            vreg = *(const uint4*)(vptr + 64);
            kN0 = *(const short8*)(kb);
            kN1 = *(const short8*)(kb + 512);
            kN2 = *(const short8*)(kb + 1024);
            kN3 = *(const short8*)(kb + 1536);
        }

        // QK^T with bias in the C operand: sf = Q.K + (bias - MSTAT)
        f32x4 sf[4];
        float pv[4][4];
        const bool clampit = tail && (it == ntiles - 1);
        if (!clampit) {
            #pragma unroll
            for (int st = 0; st < 4; ++st) {
                f32x4 cb;
                #pragma unroll
                for (int reg = 0; reg < 4; ++reg) {
                    unsigned ub = (unsigned)(baseb[reg] + offb[st]);
                    cb[reg] = *(const float*)((const char*)btm_s + ub);
                }
                short8 kf = st == 0 ? kC0 : st == 1 ? kC1 : st == 2 ? kC2 : kC3;
                sf[st] = __builtin_amdgcn_mfma_f32_16x16x32_bf16(qfrag, kf, cb, 0, 0, 0);
            }
            #pragma unroll
            for (int st = 0; st < 4; ++st)
                #pragma unroll
                for (int reg = 0; reg < 4; ++reg)
                    pv[st][reg] = fexp2(sf[st][reg]);
        } else {
            #pragma unroll
            for (int st = 0; st < 4; ++st) {
                f32x4 cb;
                #pragma unroll
                for (int reg = 0; reg < 4; ++reg) {
                    unsigned ub = (unsigned)(baseb[reg] + offb[st]);
                    ub = ub > mxb ? mxb : ub;
                    cb[reg] = *(const float*)((const char*)btm_s + ub);
                }
                short8 kf = st == 0 ? kC0 : st == 1 ? kC1 : st == 2 ? kC2 : kC3;
                sf[st] = __builtin_amdgcn_mfma_f32_16x16x32_bf16(qfrag, kf, cb, 0, 0, 0);
            }
            #pragma unroll
            for (int st = 0; st < 4; ++st) {
                bool bad = (k0 + st * 16 + ln) >= N_K;
                #pragma unroll
                for (int reg = 0; reg < 4; ++reg)
                    pv[st][reg] = bad ? 0.f : fexp2(sf[st][reg]);
            }
        }

        // P -> LDS (per-wave buffer; slot-permuted to match V layout)
        #pragma unroll
        for (int reg = 0; reg < 4; ++reg) {
            uint2 pw = make_uint2(pk_bf16(pv[0][reg], pv[1][reg]),
                                  pk_bf16(pv[2][reg], pv[3][reg]));
            *(uint2*)&P_s[w][g * 4 + reg][4 * ln] = pw;
        }
        __asm__ __volatile__("" ::: "memory");   // order P_s RAW (uint2 write, short8 read)

        // PV + l row-sum (V from LDS)
        #pragma unroll
        for (int kt = 0; kt < 2; ++kt) {
            short8 af = *(const short8*)&P_s[w][ln][g * 8 + kt * 32];
            short8 b0 = *(const short8*)&Vt_s[p][ln][g * 8 + kt * 32];
            short8 b1 = *(const short8*)&Vt_s[p][ln + 16][g * 8 + kt * 32];
            acc0 = __builtin_amdgcn_mfma_f32_16x16x32_bf16(af, b0, acc0, 0, 0, 0);
            acc1 = __builtin_amdgcn_mfma_f32_16x16x32_bf16(af, b1, acc1, 0, 0, 0);
            accL = __builtin_amdgcn_mfma_f32_16x16x32_bf16(af, ones, accL, 0, 0, 0);
        }

        if (notlast) {
            int q2 = p ^ 1;
            *(uint4*)&Vt_s[q2][vrow][vc8] = vreg;
            __syncthreads();
            p = q2;
            vptr += 64;
            kb += 2048;
            kC0 = kN0; kC1 = kN1; kC2 = kN2; kC3 = kN3;
        }

        // advance key geometry: key += 64 => offb -= 256 B (or 584 B on row wrap)
        #pragma unroll
        for (int st = 0; st < 4; ++st) {
            kcc[st] += 64;
            if (kcc[st] >= 84) { kcc[st] -= 84; offb[st] -= 584; }
            else offb[st] -= 256;
        }
    }

    // accL[reg]: every col holds the same row-sum (C row = A row = q-row g*4+reg)
    const int rbase = (b * 8 + h) * N_Q + q0 + w * 16;
    #pragma unroll
    for (int reg = 0; reg < 4; ++reg) {
        int prow = ks * NROWS + rbase + g * 4 + reg;
        pacc[(size_t)prow * 32 + ln]      = acc0[reg];
        pacc[(size_t)prow * 32 + 16 + ln] = acc1[reg];
        if (ln == 0) pl[prow] = accL[reg];
    }
}

// ---- combine 8 partials + V-BN (folded) + hardswish -> bf16 plane, x4 vectorized.
// Extra 128 blocks (>= 672) convert proj_w -> bf16 into the now-dead q_y region.
__global__ __launch_bounds__(256) void combine_kernel(const float* __restrict__ pl,
                                                      const float* __restrict__ pacc,
                                                      const float* __restrict__ sums_kv,
                                                      const float* __restrict__ kv_g,
                                                      const float* __restrict__ kv_b,
                                                      unsigned short* __restrict__ attn_o,
                                                      const float* __restrict__ proj_w,
                                                      unsigned short* __restrict__ projWb)
{
    if (blockIdx.x >= 672) {   // proj_w fp32 -> bf16 (512*256 = 32768 float4, 128 blocks)
        int i = (blockIdx.x - 672) * 256 + threadIdx.x;
        float4 v = *(const float4*)(proj_w + (size_t)i * 4);
        *(uint2*)(projWb + (size_t)i * 4) = make_uint2(pk_bf16(v.x, v.y), pk_bf16(v.z, v.w));
        return;
    }
    int idx = blockIdx.x * 256 + threadIdx.x;    // NROWS*8 items, 4 channels each
    int r = idx >> 3, e4 = (idx & 7) * 4;
    float L = 0.f;
    float vs[4] = {0.f, 0.f, 0.f, 0.f};
    size_t o = (size_t)r * 32 + e4;
    #pragma unroll
    for (int s2 = 0; s2 < NSPLIT; ++s2) {
        L += pl[(size_t)s2 * NROWS + r];
        float4 vv = *(const float4*)(pacc + (size_t)s2 * NROWS * 32 + o);
        vs[0] += vv.x; vs[1] += vv.y; vs[2] += vv.z; vs[3] += vv.w;
    }
    float invL = 1.f / L;
    int q = r % N_Q;
    int bh = r / N_Q;
    int hh = bh & 7, b = bh >> 3;
    const int ch = hh * 48 + 16 + e4;
    const float invk = 1.f / 10584.f;
    float hs[4];
    #pragma unroll
    for (int u = 0; u < 4; ++u) {
        float v = vs[u];
        float mu  = sums_kv[ch + u] * invk;
        float var = fmaf(-mu, mu, sums_kv[384 + ch + u] * invk);
        float s   = kv_g[ch + u] * rsqrtf(var + 1e-5f);
        float tt  = fmaf(-mu, s, kv_b[ch + u]);
        v = fmaf(s, v * invL, tt);
        hs[u] = v * fminf(fmaxf(v + 3.f, 0.f), 6.f) * (1.f / 6.f);
    }
    *(uint2*)(attn_o + (size_t)(b * N_Q + q) * 256 + hh * 32 + e4) =
        make_uint2(pk_bf16(hs[0], hs[1]), pk_bf16(hs[2], hs[3]));
}

// ---- final BN apply ----
__global__ __launch_bounds__(256) void norm_apply(
    const float* __restrict__ Y, const float* __restrict__ sums,
    const float* __restrict__ g, const float* __restrict__ bb,
    float* __restrict__ out, int rows, int cols, float inv_rows)
{
    __shared__ float sc_s[64], sh_s[64];
    const int t = threadIdx.x;
    const int c0 = blockIdx.x * 64;
    if (t < 64) {
        int c = c0 + t;
        float mu  = sums[c] * inv_rows;
        float var = fmaf(-mu, mu, sums[cols + c] * inv_rows);
        float s   = g[c] * rsqrtf(var + 1e-5f);
        sc_s[t] = s;
        sh_s[t] = fmaf(-mu, s, bb[c]);
    }
    __syncthreads();
    const int c4 = (t & 15) * 4;
    float4 scv = *(const float4*)&sc_s[c4];
    float4 shv = *(const float4*)&sh_s[c4];
    for (int r = blockIdx.y * 16 + (t >> 4); r < rows; r += gridDim.y * 16) {
        size_t off = (size_t)r * cols + c0 + c4;
        float4 v = *(const float4*)(Y + off);
        v.x = fmaf(v.x, scv.x, shv.x);
        v.y = fmaf(v.y, scv.y, shv.y);
        v.z = fmaf(v.z, scv.z, shv.z);
        v.w = fmaf(v.w, scv.w, shv.w);
        *(float4*)(out + off) = v;
    }
}

extern "C" void kernel_launch(void* const* d_in, const int* in_sizes, int n_in,
                              void* d_out, int out_size, void* d_ws, size_t ws_size,
                              hipStream_t stream) {
    (void)n_in; (void)out_size; (void)ws_size;
    const float* x      = (const float*)d_in[0];
    const float* kv_w   = (const float*)d_in[1];
    const float* kv_g   = (const float*)d_in[2];
    const float* kv_b   = (const float*)d_in[3];
    const float* q_w    = (const float*)d_in[4];
    const float* q_g    = (const float*)d_in[5];
    const float* q_b    = (const float*)d_in[6];
    const float* proj_w = (const float*)d_in[7];
    const float* proj_g = (const float*)d_in[8];
    const float* proj_b = (const float*)d_in[9];
    const float* bias_table = (const float*)d_in[10];
    const int*   bias_idxs  = (const int*)d_in[11];
    const int    n_off = in_sizes[10] / 8;
    float* out = (float*)d_out;

    float* ws = (float*)d_ws;
    float* q_y  = ws;                                       // 344,064 f
    float* pacc = q_y + 2688 * 128;                         // 8*NROWS*32 = 5,505,024 f
    float* proj_y = pacc;
    float* pl = pacc + (size_t)NSPLIT * NROWS * 32;         // 8*NROWS = 172,032 f
    unsigned short* attn_o = (unsigned short*)(pl + (size_t)NSPLIT * NROWS);  // 688,128 u16
    unsigned short* Kp  = attn_o + 2688 * 256;              // 2*8*5292*16 u16
    unsigned short* Vpt = Kp + 2 * 8 * N_K * 16;            // 2*8*32*N_KP u16
    float* sums_kv = (float*)(Vpt + 2 * 8 * 32 * N_KP);     // 768
    float* sums_q  = sums_kv + 768;                         // 256
    float* sums_p  = sums_q + 256;                          // 1024  (2048 f contiguous)
    float* bt_r    = sums_p + 1024;                         // 8*5292

    // bf16 staging planes:
    //  Xb/kvWb/qWb overlay pacc  (consumed by gemm_qkv BEFORE attn_mfma clobbers pacc)
    //  projWb overlays q_y       (written by combine_kernel AFTER attn_mfma's last q_y read)
    unsigned short* Xb     = (unsigned short*)pacc;         // 10584*256 u16
    unsigned short* kvWb   = Xb + 10584 * 256;              // 384*256
    unsigned short* qWb    = kvWb + 384 * 256;              // 128*256
    unsigned short* projWb = (unsigned short*)q_y;          // 512*256 u16

    // 1) one-shot fp32 -> bf16 conversion of X + kv/q weights; tail block zeroes stats
    prep_bf16<<<2775, 256, 0, stream>>>(x, kv_w, q_w, Xb, sums_kv);
    // 2) kv + q GEMMs (B-once-in-LDS, A-direct, barrier-free) + prep tails
    gemm_qkv<<<1104 + 168 + 166, 256, 0, stream>>>(Xb, kvWb, qWb, bias_table, bias_idxs,
                                                   n_off, Kp, Vpt, bt_r,
                                                   q_y, sums_kv, sums_q);
    // 3) flash attention: bias-in-C, K reg-prefetch, V LDS-dbuf
    attn_mfma<<<2688, 256, 0, stream>>>(Kp, Vpt, q_y, sums_q, q_g, q_b,
                                        sums_kv, kv_g, bt_r, pl, pacc);
    // 4) combine 8 partials + V-BN + hardswish -> bf16; tail converts proj_w -> bf16
    combine_kernel<<<672 + 128, 256, 0, stream>>>(pl, pacc, sums_kv, kv_g, kv_b, attn_o,
                                                  proj_w, projWb);
    // 5) proj GEMM (B-once-in-LDS, A-direct)
    gemm_proj<<<384, 256, 0, stream>>>(attn_o, projWb, proj_y, sums_p);
    // 6) final BN -> out
    norm_apply<<<dim3(8, 84), 256, 0, stream>>>(proj_y, sums_p, proj_g, proj_b, out,
                                                2688, 512, 1.f / 2688.f);
}

// Round 13
// 178.872 us; speedup vs baseline: 1.5671x; 1.0102x over previous
//
#include <hip/hip_runtime.h>
#include <hip/hip_bf16.h>
#include <math.h>

#define N_K 5292
#define N_KP 5376     // N_K padded to multiple of 64 for permuted V layout
#define N_Q 1344
#define NH_KD 128
#define NROWS 21504   // 2*8*1344 (b,h,q) rows of partials
#define NSPLIT 8      // K-splits per (b,h) plane
#define LOG2E 1.4426950408889634f
#define MSTAT 16.0f   // static softmax shift (log2 domain), folded into bt_r

typedef float f32x4 __attribute__((ext_vector_type(4)));
typedef short short8 __attribute__((ext_vector_type(8)));

__device__ __forceinline__ float fexp2(float x) {
#if __has_builtin(__builtin_amdgcn_exp2f)
    return __builtin_amdgcn_exp2f(x);
#else
    return exp2f(x);
#endif
}

// packed f32x2 -> bf16x2 (v_cvt_pk_bf16_f32); a in low 16 bits
__device__ __forceinline__ unsigned pk_bf16(float a, float b) {
    union { __hip_bfloat162 h; unsigned u; } c;
    c.h = __float22bfloat162_rn(make_float2(a, b));
    return c.u;
}
__device__ __forceinline__ unsigned short f2bf(float a) {
    return (unsigned short)pk_bf16(a, 0.f);
}

// ---- one-shot fp32 -> bf16 conversion of X, kv_w, q_w  (+ stats zero tail block) ----
__global__ __launch_bounds__(256) void prep_bf16(
    const float* __restrict__ X, const float* __restrict__ kv_w,
    const float* __restrict__ q_w,
    unsigned short* __restrict__ Xb, float* __restrict__ sums)
{
    int i = blockIdx.x * 256 + threadIdx.x;   // float4 index into concatenated space
    if (i >= 710144) {                        // stats zero: 256 threads x 8 floats = 2048
        int j = i - 710144;
        float4 z = make_float4(0.f, 0.f, 0.f, 0.f);
        *(float4*)(sums + (size_t)j * 8)     = z;
        *(float4*)(sums + (size_t)j * 8 + 4) = z;
        return;
    }
    const float* src;
    long off;
    if (i < 677376)       { src = X;      off = i; }
    else if (i < 701952)  { src = kv_w;   off = i - 677376; }
    else                  { src = q_w;    off = i - 701952; }
    float4 v = *(const float4*)(src + off * 4);
    *(uint2*)(Xb + (size_t)i * 4) = make_uint2(pk_bf16(v.x, v.y), pk_bf16(v.z, v.w));
}

// ---- GEMM 64x64 tile body: B panel staged ONCE in LDS, A fragments direct ----
__device__ __forceinline__ void gemm_body_direct(
    const unsigned short* __restrict__ A, const unsigned short* __restrict__ W,
    long arow, int n0,
    unsigned short (*Bs)[264], f32x4 acc[4])
{
    const int t = threadIdx.x;
    const int lane = t & 63, g = lane >> 4, ln = lane & 15;

    #pragma unroll
    for (int p = 0; p < 8; ++p) {
        int i = p * 256 + t;                 // uint4 index
        int row = i >> 5, c8 = (i & 31) * 8;
        *(uint4*)&Bs[row][c8] = *(const uint4*)(W + (size_t)(n0 + row) * 256 + c8);
    }
    __syncthreads();

    const unsigned short* aptr =
        (arow >= 0) ? (A + (size_t)arow * 256 + g * 8) : (const unsigned short*)0;

    #pragma unroll
    for (int k0 = 0; k0 < 256; k0 += 32) {
        short8 ah = (short8)0;
        if (aptr) ah = *(const short8*)(aptr + k0);
        #pragma unroll
        for (int nt = 0; nt < 4; ++nt) {
            short8 bh = *(const short8*)&Bs[nt * 16 + ln][k0 + g * 8];
            acc[nt] = __builtin_amdgcn_mfma_f32_16x16x32_bf16(ah, bh, acc[nt], 0, 0, 0);
        }
    }
}

// ---- fused column stats (sum/sumsq of this block's 64 rows) ----
__device__ __forceinline__ void gemm_stats(f32x4 acc[4], float* __restrict__ sums,
                                           int n0, int Ncols, float* scratch)
{
    const int t = threadIdx.x;
    const int w = t >> 6, lane = t & 63, g = lane >> 4, ln = lane & 15;
    float s4[4], q4[4];
    #pragma unroll
    for (int nt = 0; nt < 4; ++nt) {
        float s = acc[nt][0] + acc[nt][1] + acc[nt][2] + acc[nt][3];
        float q = fmaf(acc[nt][0], acc[nt][0], fmaf(acc[nt][1], acc[nt][1],
                  fmaf(acc[nt][2], acc[nt][2], acc[nt][3] * acc[nt][3])));
        s += __shfl_xor(s, 16); s += __shfl_xor(s, 32);
        q += __shfl_xor(q, 16); q += __shfl_xor(q, 32);
        s4[nt] = s; q4[nt] = q;
    }
    __syncthreads();
    float* st_s = scratch;
    float* st_q = scratch + 256;
    if (g == 0) {
        #pragma unroll
        for (int nt = 0; nt < 4; ++nt) {
            st_s[(w * 4 + nt) * 16 + ln] = s4[nt];
            st_q[(w * 4 + nt) * 16 + ln] = q4[nt];
        }
    }
    __syncthreads();
    if (t < 64) {
        int nt = t >> 4, c = t & 15;
        float a = 0.f, b2 = 0.f;
        #pragma unroll
        for (int ww = 0; ww < 4; ++ww) {
            a  += st_s[(ww * 4 + nt) * 16 + c];
            b2 += st_q[(ww * 4 + nt) * 16 + c];
        }
        atomicAdd(&sums[n0 + nt * 16 + c], a);
        atomicAdd(&sums[Ncols + n0 + nt * 16 + c], b2);
    }
}

// ---- kv + q GEMMs + folded prep (race-free Vpt tail zero, bias remap) ----
__global__ __launch_bounds__(256) void gemm_qkv(
    const unsigned short* __restrict__ Xb, const unsigned short* __restrict__ kvWb,
    const unsigned short* __restrict__ qWb,
    const float* __restrict__ bias_table, const int* __restrict__ bias_idxs, int n_off,
    unsigned short* __restrict__ Kp, unsigned short* __restrict__ Vpt,
    float* __restrict__ bt_r,
    float* __restrict__ q_y, float* __restrict__ sums_kv, float* __restrict__ sums_q)
{
    __shared__ unsigned short Bs[64][264];   // 33792 B
    const int t = threadIdx.x;
    const int w = t >> 6, lane = t & 63, g = lane >> 4, ln = lane & 15;
    int id = blockIdx.x;

    if (id >= 1104) {
        id -= 1104;
        if (id < 168) {           // zero the 84 never-written Vpt slots per row
            int i = id * 256 + t; // 512 rows x 84 slots = 43008 (exact)
            int row = i / 84, j = i - row * 84;
            int slot;
            if (j < 20) {         // group [5248,5312): slots of keys 5292..5311
                int kap = 44 + j;
                slot = 5248 + (((kap & 15) << 2) | (kap >> 4));
            } else {              // group [5312,5376): fully padding
                slot = 5312 + (j - 20);
            }
            Vpt[(size_t)row * N_KP + slot] = 0;
        } else {                  // bias remap: bt_r = bias*log2e - MSTAT (C-operand fold)
            int i = (id - 168) * 256 + t;
            if (i < 8 * N_K) {
                int h = i / N_K, j = i - h * N_K;
                bt_r[i] = fmaf(bias_table[h * n_off + bias_idxs[j]], LOG2E, -MSTAT);
            }
        }
        return;
    }

    f32x4 acc[4];
    #pragma unroll
    for (int nt = 0; nt < 4; ++nt) acc[nt] = (f32x4){0.f, 0.f, 0.f, 0.f};

    if (id < 1008) {            // kv: mtiles=166, nblk=6
        const int xcd = id & 7, id8 = id >> 3;
        const int my = xcd + (id8 / 6) * 8, ny = id8 % 6;
        if (my >= 166) return;
        const int m0 = my * 64, n0 = ny * 64;
        int arow0 = m0 + w * 16 + ln;
        long arow = (arow0 < 10584) ? arow0 : -1;
        gemm_body_direct(Xb, kvWb, arow, n0, Bs, acc);

        #pragma unroll
        for (int nt = 0; nt < 4; ++nt) {
            int c = n0 + nt * 16 + ln;
            int hh = c / 48, cc = c - 48 * hh;
            #pragma unroll
            for (int reg = 0; reg < 4; ++reg) {
                int mr = m0 + w * 16 + g * 4 + reg;
                if (mr < 10584) {
                    int bb = mr >= N_K;
                    int key = mr - bb * N_K;
                    unsigned short v16 = f2bf(acc[nt][reg]);
                    if (cc < 16) {
                        Kp[((size_t)(bb * 8 + hh) * N_K + key) * 16 + cc] = v16;
                    } else {
                        int kap = key & 63;
                        int keyp = (key & ~63) | (((kap & 15) << 2) | (kap >> 4));
                        Vpt[((size_t)(bb * 8 + hh) * 32 + cc - 16) * N_KP + keyp] = v16;
                    }
                }
            }
        }
        gemm_stats(acc, sums_kv, n0, 384, (float*)&Bs[0][0]);
    } else {                    // q: mtiles=42, nblk=2 (strided subsample rows)
        id -= 1008;
        const int xcd = id & 7, id8 = id >> 3;
        const int my = xcd + (id8 / 2) * 8, ny = id8 % 2;
        if (my >= 42) return;
        const int m0 = my * 64, n0 = ny * 64;
        int mrow = m0 + w * 16 + ln;
        int bb = mrow / N_Q;
        int i = mrow - bb * N_Q;
        long arow = (long)(bb * N_K + (i / 42) * 168 + (i % 42) * 2);
        gemm_body_direct(Xb, qWb, arow, n0, Bs, acc);

        #pragma unroll
        for (int nt = 0; nt < 4; ++nt)
            #pragma unroll
            for (int reg = 0; reg < 4; ++reg) {
                int mr = m0 + w * 16 + g * 4 + reg;
                q_y[(size_t)mr * 128 + n0 + nt * 16 + ln] = acc[nt][reg];
            }
        gemm_stats(acc, sums_q, n0, 128, (float*)&Bs[0][0]);
    }
}

// ---- proj GEMM (A bf16 attn_o direct, W bf16 staged once) ----
__global__ __launch_bounds__(256) void gemm_proj(
    const unsigned short* __restrict__ Ap, const unsigned short* __restrict__ Wp,
    float* __restrict__ Y, float* __restrict__ sums)
{
    __shared__ unsigned short Bs[64][264];
    const int t = threadIdx.x;
    const int w = t >> 6, lane = t & 63, g = lane >> 4, ln = lane & 15;
    const int id = blockIdx.x;
    const int xcd = id & 7, id8 = id >> 3;
    const int my = xcd + (id8 / 8) * 8, ny = id8 % 8;
    if (my >= 42) return;
    const int m0 = my * 64, n0 = ny * 64;

    f32x4 acc[4];
    #pragma unroll
    for (int nt = 0; nt < 4; ++nt) acc[nt] = (f32x4){0.f, 0.f, 0.f, 0.f};
    gemm_body_direct(Ap, Wp, (long)(m0 + w * 16 + ln), n0, Bs, acc);

    #pragma unroll
    for (int nt = 0; nt < 4; ++nt)
        #pragma unroll
        for (int reg = 0; reg < 4; ++reg) {
            int mr = m0 + w * 16 + g * 4 + reg;
            Y[(size_t)mr * 512 + n0 + nt * 16 + ln] = acc[nt][reg];
        }
    gemm_stats(acc, sums, n0, 512, (float*)&Bs[0][0]);
}

// ---- MFMA flash attention: 8-way K split; bias via MFMA C-operand (f32 LDS,
// -MSTAT pre-folded); K prefetched one tile ahead into registers, exec-masked
// to lanes<32 (upper lanes' B slots multiply against A==0; zero-init keeps
// them finite); V LDS-dbuf; bf16 partial output. LDS 27728 B.
// grid 2688: h=id&7, z=(id>>3)&15 (b*8+ks), qt=id>>7.
__global__ __launch_bounds__(256, 4) void attn_mfma(
    const unsigned short* __restrict__ Kp, const unsigned short* __restrict__ Vpt,
    const float* __restrict__ q_y, const float* __restrict__ sums_q,
    const float* __restrict__ q_g, const float* __restrict__ q_b,
    const float* __restrict__ sums_kv, const float* __restrict__ kv_g,
    const float* __restrict__ bt_r,
    float* __restrict__ pl, unsigned short* __restrict__ pacc)
{
    const int id = blockIdx.x;
    const int h = id & 7;
    const int z = (id >> 3) & 15;
    const int qt = id >> 7;
    const int b = z >> 3, ks = z & 7;
    const int t = threadIdx.x;
    const int w = t >> 6, lane = t & 63, g = lane >> 4, ln = lane & 15;

    __shared__ float btm_s[14 * 166];          // 9296 B mirrored bias (f32, -MSTAT folded)
    __shared__ unsigned short Vt_s[2][32][72]; // 9216 B (dbuf, b128-read free)
    __shared__ unsigned short P_s[4][16][72];  // 9216 B (per wave)

    const int q0 = qt * 64;
    const int t0 = (ks * 83) >> 3;
    const int t1 = ((ks + 1) * 83) >> 3;
    const int kstart = t0 * 64;
    const int kend0 = t1 * 64;
    const int kend = kend0 < N_K ? kend0 : N_K;
    const int ntiles = t1 - t0;
    const bool tail = (ks == 7);

    // mirrored-window extents; rows <= 14
    const int kr0 = kstart / 84;
    const int kr1 = (kend - 1) / 84;
    const int rq2min = (q0 / 42) * 2;
    const int rq2max = ((q0 + 63) / 42) * 2;
    const int dmin_r = rq2min - kr1;
    const int rows = (rq2max - kr0) - dmin_r + 1;
    const int nb = rows * 166;
    const unsigned mxb = (unsigned)((nb - 1) * 4);   // byte clamp (tail-last tile only)
    {   // stage mirrored f32 bias: btm[j*166+i] = bt[|dmin_r+j|*84 + |i-83|]
        const float* src = bt_r + h * N_K;
        for (int j = t; j < nb; j += 256) {
            int rr = j / 166, ii = j - rr * 166;
            int dr = dmin_r + rr; dr = dr < 0 ? -dr : dr;
            int dc = ii - 83; dc = dc < 0 ? -dc : dc;
            btm_s[j] = src[dr * 84 + dc];
        }
    }

    // Q A-fragment: q-BN (0.25*log2e folded) times K-channel BN scale
    short8 qfrag = (short8)0;
    if (lane < 32) {
        const float invq = 1.f / 2688.f, invk = 1.f / 10584.f;
        const float post = 0.25f * LOG2E;
        const int c0 = h * 16 + g * 8;
        const int ck = h * 48 + g * 8;
        const float* qp = q_y + (size_t)(b * N_Q + q0 + w * 16 + ln) * NH_KD + c0;
        float vv[8];
        #pragma unroll
        for (int j = 0; j < 8; ++j) {
            float mu  = sums_q[c0 + j] * invq;
            float var = fmaf(-mu, mu, sums_q[128 + c0 + j] * invq);
            float s   = q_g[c0 + j] * rsqrtf(var + 1e-5f) * post;
            float vq  = fmaf(qp[j], s, fmaf(-mu, s, q_b[c0 + j] * post));
            float muk = sums_kv[ck + j] * invk;
            float vrk = fmaf(-muk, muk, sums_kv[384 + ck + j] * invk);
            float sk  = kv_g[ck + j] * rsqrtf(vrk + 1e-5f);
            vv[j] = vq * sk;
        }
        union { short8 s; unsigned u[4]; } qf;
        qf.u[0] = pk_bf16(vv[0], vv[1]); qf.u[1] = pk_bf16(vv[2], vv[3]);
        qf.u[2] = pk_bf16(vv[4], vv[5]); qf.u[3] = pk_bf16(vv[6], vv[7]);
        qfrag = qf.s;
    }

    // all-ones bf16 B-fragment (for MFMA row-sum of P -> l)
    union { short8 s; unsigned u[4]; } onef;
    #pragma unroll
    for (int j = 0; j < 4; ++j) onef.u[j] = 0x3F803F80u;
    const short8 ones = onef.s;

    // per-reg base BYTE offset into mirrored f32 table (constant over key loop)
    int baseb[4];
    #pragma unroll
    for (int reg = 0; reg < 4; ++reg) {
        int qg = q0 + w * 16 + g * 4 + reg;
        int rq2 = (qg / 42) * 2;
        int cq2 = (qg % 42) * 2;
        baseb[reg] = ((rq2 - dmin_r) * 166 + cq2 + 83) * 4;
    }
    // per-subtile BYTE offset, advanced incrementally: off = -(kr*166 + kc)*4
    int offb[4], kcc[4];
    #pragma unroll
    for (int st = 0; st < 4; ++st) {
        int kg = kstart + st * 16 + ln;
        int okr = kg / 84;
        kcc[st] = kg - okr * 84;
        offb[st] = -(okr * 166 + kcc[st]) * 4;
    }

    // K: rolling direct-global byte pointer, exec-masked to lanes<32 (zero-init
    // elsewhere keeps the B operand finite; products are 0 since qfrag==0 there).
    const char* kb = (const char*)(Kp + (size_t)(b * 8 + h) * N_K * 16)
                   + (size_t)kstart * 32 + ln * 32 + g * 16;
    short8 kC0 = (short8)0, kC1 = (short8)0, kC2 = (short8)0, kC3 = (short8)0;
    short8 kN0 = (short8)0, kN1 = (short8)0, kN2 = (short8)0, kN3 = (short8)0;
    if (lane < 32) {
        kC0 = *(const short8*)(kb);
        kC1 = *(const short8*)(kb + 512);
        kC2 = *(const short8*)(kb + 1024);
        kC3 = *(const short8*)(kb + 1536);
    }
    kb += 2048;

    // V: LDS-staged dbuf (coalesced b128 stage)
    const int vrow = t >> 3, vc8 = (t & 7) * 8;
    const unsigned short* vptr = Vpt + (size_t)(b * 8 + h) * 32 * N_KP
                                     + (size_t)vrow * N_KP + kstart + vc8;
    uint4 vreg = *(const uint4*)vptr;
    *(uint4*)&Vt_s[0][vrow][vc8] = vreg;
    __syncthreads();   // V(0) + bias table ready

    f32x4 acc0 = {0.f, 0.f, 0.f, 0.f}, acc1 = {0.f, 0.f, 0.f, 0.f};
    f32x4 accL = {0.f, 0.f, 0.f, 0.f};              // l via MFMA(P, ones)
    int p = 0;

    for (int it = 0; it < ntiles; ++it) {
        const int k0 = kstart + it * 64;
        const bool notlast = (it + 1 < ntiles);
        if (notlast) {   // issue next-tile loads early (latency hides under exp/PV)
            vreg = *(const uint4*)(vptr + 64);
            if (lane < 32) {
                kN0 = *(const short8*)(kb);
                kN1 = *(const short8*)(kb + 512);
                kN2 = *(const short8*)(kb + 1024);
                kN3 = *(const short8*)(kb + 1536);
            }
        }

        // QK^T with bias in the C operand: sf = Q.K + (bias - MSTAT)
        f32x4 sf[4];
        float pv[4][4];
        const bool clampit = tail && (it == ntiles - 1);
        if (!clampit) {
            #pragma unroll
            for (int st = 0; st < 4; ++st) {
                f32x4 cb;
                #pragma unroll
                for (int reg = 0; reg < 4; ++reg) {
                    unsigned ub = (unsigned)(baseb[reg] + offb[st]);
                    cb[reg] = *(const float*)((const char*)btm_s + ub);
                }
                short8 kf = st == 0 ? kC0 : st == 1 ? kC1 : st == 2 ? kC2 : kC3;
                sf[st] = __builtin_amdgcn_mfma_f32_16x16x32_bf16(qfrag, kf, cb, 0, 0, 0);
            }
            #pragma unroll
            for (int st = 0; st < 4; ++st)
                #pragma unroll
                for (int reg = 0; reg < 4; ++reg)
                    pv[st][reg] = fexp2(sf[st][reg]);
        } else {
            #pragma unroll
            for (int st = 0; st < 4; ++st) {
                f32x4 cb;
                #pragma unroll
                for (int reg = 0; reg < 4; ++reg) {
                    unsigned ub = (unsigned)(baseb[reg] + offb[st]);
                    ub = ub > mxb ? mxb : ub;
                    cb[reg] = *(const float*)((const char*)btm_s + ub);
                }
                short8 kf = st == 0 ? kC0 : st == 1 ? kC1 : st == 2 ? kC2 : kC3;
                sf[st] = __builtin_amdgcn_mfma_f32_16x16x32_bf16(qfrag, kf, cb, 0, 0, 0);
            }
            #pragma unroll
            for (int st = 0; st < 4; ++st) {
                bool bad = (k0 + st * 16 + ln) >= N_K;
                #pragma unroll
                for (int reg = 0; reg < 4; ++reg)
                    pv[st][reg] = bad ? 0.f : fexp2(sf[st][reg]);
            }
        }

        // P -> LDS (per-wave buffer; slot-permuted to match V layout)
        #pragma unroll
        for (int reg = 0; reg < 4; ++reg) {
            uint2 pw = make_uint2(pk_bf16(pv[0][reg], pv[1][reg]),
                                  pk_bf16(pv[2][reg], pv[3][reg]));
            *(uint2*)&P_s[w][g * 4 + reg][4 * ln] = pw;
        }
        __asm__ __volatile__("" ::: "memory");   // order P_s RAW (uint2 write, short8 read)

        // PV + l row-sum (V from LDS)
        #pragma unroll
        for (int kt = 0; kt < 2; ++kt) {
            short8 af = *(const short8*)&P_s[w][ln][g * 8 + kt * 32];
            short8 b0 = *(const short8*)&Vt_s[p][ln][g * 8 + kt * 32];
            short8 b1 = *(const short8*)&Vt_s[p][ln + 16][g * 8 + kt * 32];
            acc0 = __builtin_amdgcn_mfma_f32_16x16x32_bf16(af, b0, acc0, 0, 0, 0);
            acc1 = __builtin_amdgcn_mfma_f32_16x16x32_bf16(af, b1, acc1, 0, 0, 0);
            accL = __builtin_amdgcn_mfma_f32_16x16x32_bf16(af, ones, accL, 0, 0, 0);
        }

        if (notlast) {
            int q2 = p ^ 1;
            *(uint4*)&Vt_s[q2][vrow][vc8] = vreg;
            __syncthreads();
            p = q2;
            vptr += 64;
            kb += 2048;
            kC0 = kN0; kC1 = kN1; kC2 = kN2; kC3 = kN3;
        }

        // advance key geometry: key += 64 => offb -= 256 B (or 584 B on row wrap)
        #pragma unroll
        for (int st = 0; st < 4; ++st) {
            kcc[st] += 64;
            if (kcc[st] >= 84) { kcc[st] -= 84; offb[st] -= 584; }
            else offb[st] -= 256;
        }
    }

    // bf16 partial output (halves pacc traffic; 8 partials re-summed in f32)
    const int rbase = (b * 8 + h) * N_Q + q0 + w * 16;
    #pragma unroll
    for (int reg = 0; reg < 4; ++reg) {
        int prow = ks * NROWS + rbase + g * 4 + reg;
        unsigned short* pb = pacc + (size_t)prow * 32;
        pb[ln]      = f2bf(acc0[reg]);
        pb[16 + ln] = f2bf(acc1[reg]);
        if (ln == 0) pl[prow] = accL[reg];
    }
}

// ---- combine 8 bf16 partials + V-BN (folded) + hardswish -> bf16 plane.
// Extra 128 blocks (>= 672) convert proj_w -> bf16 into the now-dead q_y region.
__global__ __launch_bounds__(256) void combine_kernel(const float* __restrict__ pl,
                                                      const unsigned short* __restrict__ pacc,
                                                      const float* __restrict__ sums_kv,
                                                      const float* __restrict__ kv_g,
                                                      const float* __restrict__ kv_b,
                                                      unsigned short* __restrict__ attn_o,
                                                      const float* __restrict__ proj_w,
                                                      unsigned short* __restrict__ projWb)
{
    if (blockIdx.x >= 672) {   // proj_w fp32 -> bf16 (512*256 = 32768 float4, 128 blocks)
        int i = (blockIdx.x - 672) * 256 + threadIdx.x;
        float4 v = *(const float4*)(proj_w + (size_t)i * 4);
        *(uint2*)(projWb + (size_t)i * 4) = make_uint2(pk_bf16(v.x, v.y), pk_bf16(v.z, v.w));
        return;
    }
    int idx = blockIdx.x * 256 + threadIdx.x;    // NROWS*8 items, 4 channels each
    int r = idx >> 3, e4 = (idx & 7) * 4;
    float L = 0.f;
    float vs[4] = {0.f, 0.f, 0.f, 0.f};
    size_t o = (size_t)r * 32 + e4;
    #pragma unroll
    for (int s2 = 0; s2 < NSPLIT; ++s2) {
        L += pl[(size_t)s2 * NROWS + r];
        uint2 pv2 = *(const uint2*)(pacc + (size_t)s2 * NROWS * 32 + o);
        vs[0] += __uint_as_float((pv2.x & 0xffffu) << 16);
        vs[1] += __uint_as_float(pv2.x & 0xffff0000u);
        vs[2] += __uint_as_float((pv2.y & 0xffffu) << 16);
        vs[3] += __uint_as_float(pv2.y & 0xffff0000u);
    }
    float invL = 1.f / L;
    int q = r % N_Q;
    int bh = r / N_Q;
    int hh = bh & 7, b = bh >> 3;
    const int ch = hh * 48 + 16 + e4;
    const float invk = 1.f / 10584.f;
    float hs[4];
    #pragma unroll
    for (int u = 0; u < 4; ++u) {
        float v = vs[u];
        float mu  = sums_kv[ch + u] * invk;
        float var = fmaf(-mu, mu, sums_kv[384 + ch + u] * invk);
        float s   = kv_g[ch + u] * rsqrtf(var + 1e-5f);
        float tt  = fmaf(-mu, s, kv_b[ch + u]);
        v = fmaf(s, v * invL, tt);
        hs[u] = v * fminf(fmaxf(v + 3.f, 0.f), 6.f) * (1.f / 6.f);
    }
    *(uint2*)(attn_o + (size_t)(b * N_Q + q) * 256 + hh * 32 + e4) =
        make_uint2(pk_bf16(hs[0], hs[1]), pk_bf16(hs[2], hs[3]));
}

// ---- final BN apply ----
__global__ __launch_bounds__(256) void norm_apply(
    const float* __restrict__ Y, const float* __restrict__ sums,
    const float* __restrict__ g, const float* __restrict__ bb,
    float* __restrict__ out, int rows, int cols, float inv_rows)
{
    __shared__ float sc_s[64], sh_s[64];
    const int t = threadIdx.x;
    const int c0 = blockIdx.x * 64;
    if (t < 64) {
        int c = c0 + t;
        float mu  = sums[c] * inv_rows;
        float var = fmaf(-mu, mu, sums[cols + c] * inv_rows);
        float s   = g[c] * rsqrtf(var + 1e-5f);
        sc_s[t] = s;
        sh_s[t] = fmaf(-mu, s, bb[c]);
    }
    __syncthreads();
    const int c4 = (t & 15) * 4;
    float4 scv = *(const float4*)&sc_s[c4];
    float4 shv = *(const float4*)&sh_s[c4];
    for (int r = blockIdx.y * 16 + (t >> 4); r < rows; r += gridDim.y * 16) {
        size_t off = (size_t)r * cols + c0 + c4;
        float4 v = *(const float4*)(Y + off);
        v.x = fmaf(v.x, scv.x, shv.x);
        v.y = fmaf(v.y, scv.y, shv.y);
        v.z = fmaf(v.z, scv.z, shv.z);
        v.w = fmaf(v.w, scv.w, shv.w);
        *(float4*)(out + off) = v;
    }
}

extern "C" void kernel_launch(void* const* d_in, const int* in_sizes, int n_in,
                              void* d_out, int out_size, void* d_ws, size_t ws_size,
                              hipStream_t stream) {
    (void)n_in; (void)out_size; (void)ws_size;
    const float* x      = (const float*)d_in[0];
    const float* kv_w   = (const float*)d_in[1];
    const float* kv_g   = (const float*)d_in[2];
    const float* kv_b   = (const float*)d_in[3];
    const float* q_w    = (const float*)d_in[4];
    const float* q_g    = (const float*)d_in[5];
    const float* q_b    = (const float*)d_in[6];
    const float* proj_w = (const float*)d_in[7];
    const float* proj_g = (const float*)d_in[8];
    const float* proj_b = (const float*)d_in[9];
    const float* bias_table = (const float*)d_in[10];
    const int*   bias_idxs  = (const int*)d_in[11];
    const int    n_off = in_sizes[10] / 8;
    float* out = (float*)d_out;

    float* ws = (float*)d_ws;
    float* q_y  = ws;                                       // 344,064 f
    unsigned short* pacc_b = (unsigned short*)(q_y + 2688 * 128);  // 8*NROWS*32 u16 = 11 MB
    float* proj_y = (float*)pacc_b;                         // 1,376,256 f (fits in region)
    float* pl = (float*)(pacc_b + (size_t)NSPLIT * NROWS * 32);   // 8*NROWS f
    unsigned short* attn_o = (unsigned short*)(pl + (size_t)NSPLIT * NROWS);  // 688,128 u16
    unsigned short* Kp  = attn_o + 2688 * 256;              // 2*8*5292*16 u16
    unsigned short* Vpt = Kp + 2 * 8 * N_K * 16;            // 2*8*32*N_KP u16
    float* sums_kv = (float*)(Vpt + 2 * 8 * 32 * N_KP);     // 768
    float* sums_q  = sums_kv + 768;                         // 256
    float* sums_p  = sums_q + 256;                          // 1024  (2048 f contiguous)
    float* bt_r    = sums_p + 1024;                         // 8*5292

    // bf16 staging planes:
    //  Xb/kvWb/qWb overlay pacc_b (consumed by gemm_qkv BEFORE attn_mfma clobbers it)
    //  projWb overlays q_y        (written by combine_kernel AFTER attn_mfma's last q_y read)
    unsigned short* Xb     = pacc_b;                        // 10584*256 u16
    unsigned short* kvWb   = Xb + 10584 * 256;              // 384*256
    unsigned short* qWb    = kvWb + 384 * 256;              // 128*256
    unsigned short* projWb = (unsigned short*)q_y;          // 512*256 u16

    // 1) one-shot fp32 -> bf16 conversion of X + kv/q weights; tail block zeroes stats
    prep_bf16<<<2775, 256, 0, stream>>>(x, kv_w, q_w, Xb, sums_kv);
    // 2) kv + q GEMMs (B-once-in-LDS, A-direct, barrier-free) + prep tails
    gemm_qkv<<<1104 + 168 + 166, 256, 0, stream>>>(Xb, kvWb, qWb, bias_table, bias_idxs,
                                                   n_off, Kp, Vpt, bt_r,
                                                   q_y, sums_kv, sums_q);
    // 3) flash attention: bias-in-C, masked K reg-prefetch, V LDS-dbuf, bf16 partials
    attn_mfma<<<2688, 256, 0, stream>>>(Kp, Vpt, q_y, sums_q, q_g, q_b,
                                        sums_kv, kv_g, bt_r, pl, pacc_b);
    // 4) combine 8 bf16 partials + V-BN + hardswish -> bf16; tail converts proj_w
    combine_kernel<<<672 + 128, 256, 0, stream>>>(pl, pacc_b, sums_kv, kv_g, kv_b, attn_o,
                                                  proj_w, projWb);
    // 5) proj GEMM (B-once-in-LDS, A-direct)
    gemm_proj<<<384, 256, 0, stream>>>(attn_o, projWb, proj_y, sums_p);
    // 6) final BN -> out
    norm_apply<<<dim3(8, 84), 256, 0, stream>>>(proj_y, sums_p, proj_g, proj_b, out,
                                                2688, 512, 1.f / 2688.f);
}